// Round 1
// baseline (785.425 us; speedup 1.0000x reference)
//
#include <hip/hip_runtime.h>
#include <math.h>

constexpr int Bb = 64;
constexpr int Ss = 1024;
constexpr int Ff = 128;
constexpr int G2 = 256;   // 2F
constexpr int Kk = 64;
constexpr int NE = 1152;  // S + 64 (W^T cols) + 64 pad

typedef __bf16 bfrag __attribute__((ext_vector_type(8)));
typedef float  facc  __attribute__((ext_vector_type(4)));
typedef short  s8v   __attribute__((ext_vector_type(8)));
typedef short  s4v   __attribute__((ext_vector_type(4)));

__device__ __forceinline__ short f2bfs(float f) {
  union { float f; unsigned u; } v; v.f = f;
  unsigned r = v.u + 0x7FFFu + ((v.u >> 16) & 1u);
  return (short)(r >> 16);
}
__device__ __forceinline__ float bf2fs(short s) {
  union { unsigned u; float f; } v; v.u = ((unsigned)(unsigned short)s) << 16;
  return v.f;
}
__device__ __forceinline__ facc mfma16(bfrag a, bfrag b, facc c) {
  return __builtin_amdgcn_mfma_f32_16x16x32_bf16(a, b, c, 0, 0, 0);
}

// ---------------- K0a: transpose+convert x -> xT bf16 [3][B][F][S] ------------
__global__ void k_transpose(const float* __restrict__ aud, const float* __restrict__ vis,
                            const float* __restrict__ txt, short* __restrict__ xT) {
  __shared__ float tile[64][65];
  int z = blockIdx.z;                 // mod*B + b
  int mod = z >> 6, b = z & 63;
  const float* x = (mod == 0) ? aud : (mod == 1) ? vis : txt;
  int s0 = blockIdx.x * 64, f0 = blockIdx.y * 64;
  int tid = threadIdx.x;
  for (int i = 0; i < 16; ++i) {
    int idx = i * 256 + tid;
    int si = idx >> 6, fi = idx & 63;
    tile[si][fi] = x[((size_t)b * Ss + s0 + si) * Ff + f0 + fi];
  }
  __syncthreads();
  short* dst = xT + ((size_t)mod * Bb + b) * Ff * Ss;
  for (int i = 0; i < 16; ++i) {
    int idx = i * 256 + tid;
    int fi = idx >> 6, si = idx & 63;
    dst[(size_t)(f0 + fi) * Ss + s0 + si] = f2bfs(tile[si][fi]);
  }
}

// ---------------- K0b: build Aext bf16 [3][S][NE] = [A | W^T | 0] -------------
__global__ void k_build_aext(const float* __restrict__ Aa, const float* __restrict__ Av,
                             const float* __restrict__ Al, const float* __restrict__ Wa,
                             const float* __restrict__ Wv, const float* __restrict__ Wt,
                             short* __restrict__ aext) {
  int idx = blockIdx.x * 256 + threadIdx.x;   // < 3*Ss*NE
  int mod = idx / (Ss * NE);
  int rem = idx - mod * (Ss * NE);
  int t = rem / NE, n = rem - t * NE;
  const float* A = (mod == 0) ? Aa : (mod == 1) ? Av : Al;
  const float* W = (mod == 0) ? Wa : (mod == 1) ? Wv : Wt;
  float v = 0.f;
  if (n < Ss) v = A[t * Ss + n];
  else if (n < Ss + Kk) v = W[(n - Ss) * Ss + t];
  aext[idx] = f2bfs(v);
}

// ---------------- K0c: convert Wc [3][K][2F], Wh [3][S][K] to bf16 ------------
__global__ void k_build_w(const float* __restrict__ Wca, const float* __restrict__ Wcv,
                          const float* __restrict__ Wct, const float* __restrict__ Wha,
                          const float* __restrict__ Whv, const float* __restrict__ Wht,
                          short* __restrict__ wcb, short* __restrict__ whb) {
  int idx = blockIdx.x * 256 + threadIdx.x;
  const int n1 = 3 * Kk * G2;                // 49152
  if (idx < n1) {
    int mod = idx / (Kk * G2), r = idx - mod * (Kk * G2);
    const float* W = (mod == 0) ? Wca : (mod == 1) ? Wcv : Wct;
    wcb[idx] = f2bfs(W[r]);
  } else {
    int j = idx - n1;                        // < 3*Ss*Kk
    int mod = j / (Ss * Kk), r = j - mod * (Ss * Kk);
    const float* W = (mod == 0) ? Wha : (mod == 1) ? Whv : Wht;
    whb[j] = f2bfs(W[r]);
  }
}

// ---------------- K1: AMLP f-GEMM, pooled p out + global sum(f^2) -------------
__global__ void __launch_bounds__(256) k_amlp(
    const float* __restrict__ txt, const float* __restrict__ aud, const float* __restrict__ vis,
    const float* __restrict__ Wi, const float* __restrict__ bi,
    const float* __restrict__ Wq, const float* __restrict__ bq,
    const float* __restrict__ Wvp, const float* __restrict__ bvp,
    short* __restrict__ p1, short* __restrict__ p2, float* __restrict__ sumsq) {
  int mod = blockIdx.y;
  const float* x    = (mod == 0) ? txt : (mod == 1) ? aud : vis;
  const float* W    = (mod == 0) ? Wi  : (mod == 1) ? Wq  : Wvp;
  const float* bias = (mod == 0) ? bi  : (mod == 1) ? bq  : bvp;
  short* pout = (mod == 0) ? p1 : (mod == 1) ? p2 : nullptr;

  // LDS weight layout: [(k>>3)][n][k&7]  -> fragment-contiguous 16B reads
  __shared__ short wlds[G2 * Ff];   // 64KB
  __shared__ float wred[4];
  int tid = threadIdx.x, lane = tid & 63, wave = tid >> 6;
  int quad = lane >> 4, nl = lane & 15;
  for (int i = 0; i < 32; ++i) {
    int idx4 = i * 256 + tid;       // over 8192 float4-quads
    int n = idx4 >> 5, k4 = (idx4 & 31) * 4;
    float4 w4 = *(const float4*)(W + n * Ff + k4);
    int base = ((k4 >> 3) * G2 + n) * 8 + (k4 & 7);
    wlds[base + 0] = f2bfs(w4.x); wlds[base + 1] = f2bfs(w4.y);
    wlds[base + 2] = f2bfs(w4.z); wlds[base + 3] = f2bfs(w4.w);
  }
  __syncthreads();

  int arow = blockIdx.x * 64 + wave * 16 + nl;     // A-operand row (m = lane&15)
  const float* xrow = x + (size_t)arow * Ff;
  facc zero = {0.f, 0.f, 0.f, 0.f};
  facc acc[16];
  for (int t = 0; t < 16; ++t) acc[t] = zero;
  for (int k0 = 0; k0 < Ff; k0 += 32) {
    float4 a0 = *(const float4*)(xrow + k0 + quad * 8);
    float4 a1 = *(const float4*)(xrow + k0 + quad * 8 + 4);
    bfrag af;
    af[0]=(__bf16)a0.x; af[1]=(__bf16)a0.y; af[2]=(__bf16)a0.z; af[3]=(__bf16)a0.w;
    af[4]=(__bf16)a1.x; af[5]=(__bf16)a1.y; af[6]=(__bf16)a1.z; af[7]=(__bf16)a1.w;
    int chunk = (k0 >> 3) + quad;
    for (int t = 0; t < 16; ++t) {
      bfrag bfr = *(const bfrag*)(wlds + ((size_t)chunk * G2 + t * 16 + nl) * 8);
      acc[t] = mfma16(af, bfr, acc[t]);
    }
  }

  float sq = 0.f;
  int drow = blockIdx.x * 64 + wave * 16 + quad * 4;  // D row base (m = quad*4+r)
  for (int t = 0; t < 16; ++t) {
    float bia = bias[t * 16 + nl];
    for (int r = 0; r < 4; ++r) {
      float fv = acc[t][r] + bia;
      sq += fv * fv;
      if (pout) {
        float fo = fv + __shfl_xor(fv, 1, 64);       // pair-pool along n
        if ((lane & 1) == 0)
          pout[(size_t)(drow + r) * Ff + t * 8 + (nl >> 1)] = f2bfs(fo);
      }
    }
  }
  for (int off = 32; off > 0; off >>= 1) sq += __shfl_down(sq, off, 64);
  if (lane == 0) wred[wave] = sq;
  __syncthreads();
  if (tid == 0) atomicAdd(&sumsq[mod], wred[0] + wred[1] + wred[2] + wred[3]);
}

// ---------------- K2: column norms over s of z -------------------------------
__global__ void k_colnorm(const short* __restrict__ p1, const short* __restrict__ p2,
                          const float* __restrict__ sumsq, float* __restrict__ colnsq) {
  float n1 = sqrtf(sumsq[0]), n2 = sqrtf(sumsq[1]), n3 = sqrtf(sumsq[2]);
  float w1 = n1 / (n1 + n2), w2 = n2 / (n1 + n2);
  float tc = 2.f * n3 * n3 / (n1 + n2 + n3);
  int b = blockIdx.x, j = threadIdx.x;
  int s0 = blockIdx.y * 64;
  float a = 0.f;
  for (int s = s0; s < s0 + 64; ++s) {
    size_t off = ((size_t)b * Ss + s) * Ff + j;
    float z = w1 * bf2fs(p1[off]) + w2 * bf2fs(p2[off]) + tc;
    a += z * z;
  }
  atomicAdd(&colnsq[b * Ff + j], a);
}

// ---------------- K3: G = z / max(colnorm, 1e-12), bf16 ----------------------
__global__ void k_gnorm(const short* __restrict__ p1, const short* __restrict__ p2,
                        const float* __restrict__ sumsq, const float* __restrict__ colnsq,
                        short* __restrict__ g) {
  float n1 = sqrtf(sumsq[0]), n2 = sqrtf(sumsq[1]), n3 = sqrtf(sumsq[2]);
  float w1 = n1 / (n1 + n2), w2 = n2 / (n1 + n2);
  float tc = 2.f * n3 * n3 / (n1 + n2 + n3);
  int idx = (blockIdx.x * 256 + threadIdx.x) * 4;
  int b = idx >> 17;                 // / (Ss*Ff)
  int j0 = idx & (Ff - 1);
  s4v v1 = *(const s4v*)(p1 + idx);
  s4v v2 = *(const s4v*)(p2 + idx);
  s4v out;
  for (int c = 0; c < 4; ++c) {
    float z = w1 * bf2fs(v1[c]) + w2 * bf2fs(v2[c]) + tc;
    float cn = fmaxf(sqrtf(colnsq[b * Ff + j0 + c]), 1e-12f);
    out[c] = f2bfs(z / cn);
  }
  *(s4v*)(g + idx) = out;
}

// ---------------- K4: M-GEMM  [8192,1024]x[1024,1152] per modality -----------
__global__ void __launch_bounds__(256) k_mgemm(const short* __restrict__ xT,
                                               const short* __restrict__ aext,
                                               short* __restrict__ mxext) {
  int mod = blockIdx.z;
  const short* Ap = xT + (size_t)mod * Bb * Ff * Ss;
  const short* Bp = aext + (size_t)mod * Ss * NE;
  short* Op = mxext + (size_t)mod * Bb * Ff * NE;
  int M0 = blockIdx.x * 128, N0 = blockIdx.y * 128;
  __shared__ short As[128 * 40];
  __shared__ short Bs[128 * 40];
  int tid = threadIdx.x, lane = tid & 63, wave = tid >> 6;
  int quad = lane >> 4, nl = lane & 15;
  int wm = (wave >> 1) * 64, wn = (wave & 1) * 64;
  facc zero = {0.f, 0.f, 0.f, 0.f};
  facc acc[4][4];
  for (int i = 0; i < 4; ++i) for (int j = 0; j < 4; ++j) acc[i][j] = zero;
  for (int k0 = 0; k0 < Ss; k0 += 32) {
    __syncthreads();
    for (int i = 0; i < 2; ++i) {
      int id8 = i * 256 + tid;
      int r = id8 >> 2, c8 = (id8 & 3) * 8;
      *(s8v*)(As + r * 40 + c8) = *(const s8v*)(Ap + (size_t)(M0 + r) * Ss + k0 + c8);
    }
    for (int i = 0; i < 2; ++i) {
      int id8 = i * 256 + tid;
      int kk = id8 >> 4, n8 = (id8 & 15) * 8;
      s8v v = *(const s8v*)(Bp + (size_t)(k0 + kk) * NE + N0 + n8);
      for (int e = 0; e < 8; ++e) Bs[(n8 + e) * 40 + kk] = v[e];
    }
    __syncthreads();
    bfrag a[4], bfr[4];
    for (int mt = 0; mt < 4; ++mt)
      a[mt] = *(const bfrag*)(As + (wm + mt * 16 + nl) * 40 + quad * 8);
    for (int nt = 0; nt < 4; ++nt)
      bfr[nt] = *(const bfrag*)(Bs + (wn + nt * 16 + nl) * 40 + quad * 8);
    for (int mt = 0; mt < 4; ++mt)
      for (int nt = 0; nt < 4; ++nt)
        acc[mt][nt] = mfma16(a[mt], bfr[nt], acc[mt][nt]);
  }
  for (int mt = 0; mt < 4; ++mt)
    for (int nt = 0; nt < 4; ++nt)
      for (int r = 0; r < 4; ++r) {
        int row = M0 + wm + mt * 16 + quad * 4 + r;
        int col = N0 + wn + nt * 16 + nl;
        Op[(size_t)row * NE + col] = f2bfs(acc[mt][nt][r]);
      }
}

// ---------------- K5: C-GEMM  C = tanh((M @ [x|G])/16) -----------------------
__global__ void __launch_bounds__(256) k_cgemm(const short* __restrict__ mxext,
                                               const float* __restrict__ txt,
                                               const float* __restrict__ aud,
                                               const short* __restrict__ g,
                                               short* __restrict__ cc) {
  int b = blockIdx.x, half = blockIdx.y, mod = blockIdx.z;
  const short* Ap = mxext + ((size_t)mod * Bb + b) * Ff * NE;
  short* Cp = cc + ((size_t)mod * Bb + b) * Ff * G2;
  // modality a and v both use aud (source bug); t uses txt
  const float* xsrc = ((mod == 2) ? txt : aud) + (size_t)b * Ss * Ff;
  const short* gsrc = g + (size_t)b * Ss * Ff;
  __shared__ short As[128 * 40];
  __shared__ short Bs[128 * 40];
  int tid = threadIdx.x, lane = tid & 63, wave = tid >> 6;
  int quad = lane >> 4, nl = lane & 15;
  int wm = (wave >> 1) * 64, wn = (wave & 1) * 64;
  facc zero = {0.f, 0.f, 0.f, 0.f};
  facc acc[4][4];
  for (int i = 0; i < 4; ++i) for (int j = 0; j < 4; ++j) acc[i][j] = zero;
  for (int k0 = 0; k0 < Ss; k0 += 32) {
    __syncthreads();
    for (int i = 0; i < 2; ++i) {
      int id8 = i * 256 + tid;
      int r = id8 >> 2, c8 = (id8 & 3) * 8;
      *(s8v*)(As + r * 40 + c8) = *(const s8v*)(Ap + (size_t)r * NE + k0 + c8);
    }
    if (half == 0) {
      for (int i = 0; i < 4; ++i) {
        int id4 = i * 256 + tid;                    // over 1024
        int kk = id4 >> 5, c4 = (id4 & 31) * 4;
        float4 v = *(const float4*)(xsrc + (size_t)(k0 + kk) * Ff + c4);
        Bs[(c4 + 0) * 40 + kk] = f2bfs(v.x);
        Bs[(c4 + 1) * 40 + kk] = f2bfs(v.y);
        Bs[(c4 + 2) * 40 + kk] = f2bfs(v.z);
        Bs[(c4 + 3) * 40 + kk] = f2bfs(v.w);
      }
    } else {
      for (int i = 0; i < 2; ++i) {
        int id8 = i * 256 + tid;
        int kk = id8 >> 4, n8 = (id8 & 15) * 8;
        s8v v = *(const s8v*)(gsrc + (size_t)(k0 + kk) * Ff + n8);
        for (int e = 0; e < 8; ++e) Bs[(n8 + e) * 40 + kk] = v[e];
      }
    }
    __syncthreads();
    bfrag a[4], bfr[4];
    for (int mt = 0; mt < 4; ++mt)
      a[mt] = *(const bfrag*)(As + (wm + mt * 16 + nl) * 40 + quad * 8);
    for (int nt = 0; nt < 4; ++nt)
      bfr[nt] = *(const bfrag*)(Bs + (wn + nt * 16 + nl) * 40 + quad * 8);
    for (int mt = 0; mt < 4; ++mt)
      for (int nt = 0; nt < 4; ++nt)
        acc[mt][nt] = mfma16(a[mt], bfr[nt], acc[mt][nt]);
  }
  for (int mt = 0; mt < 4; ++mt)
    for (int nt = 0; nt < 4; ++nt)
      for (int r = 0; r < 4; ++r) {
        int row = wm + mt * 16 + quad * 4 + r;
        int col = half * 128 + wn + nt * 16 + nl;
        Cp[(size_t)row * G2 + col] = f2bfs(tanhf(acc[mt][nt][r] * 0.0625f));
      }
}

// ---------------- K6: H = relu(C @ Wc^T + T2) --------------------------------
__global__ void k_hgemm(const short* __restrict__ cc, const short* __restrict__ wcb,
                        const short* __restrict__ mxext, short* __restrict__ h) {
  int b = blockIdx.x, mod = blockIdx.y;
  const short* Cp = cc + ((size_t)mod * Bb + b) * Ff * G2;
  const short* Wp = wcb + (size_t)mod * Kk * G2;
  const short* T2 = mxext + ((size_t)mod * Bb + b) * Ff * NE + Ss;
  short* Hp = h + ((size_t)mod * Bb + b) * Ff * Kk;
  int tid = threadIdx.x, lane = tid & 63, wave = tid >> 6;
  int quad = lane >> 4, nl = lane & 15;
  facc zero = {0.f, 0.f, 0.f, 0.f};
  facc acc[2][4];
  for (int i = 0; i < 2; ++i) for (int j = 0; j < 4; ++j) acc[i][j] = zero;
  for (int k0 = 0; k0 < G2; k0 += 32) {
    bfrag a[2], bfr[4];
    for (int mt = 0; mt < 2; ++mt)
      a[mt] = *(const bfrag*)(Cp + (size_t)(wave * 32 + mt * 16 + nl) * G2 + k0 + quad * 8);
    for (int nt = 0; nt < 4; ++nt)
      bfr[nt] = *(const bfrag*)(Wp + (size_t)(nt * 16 + nl) * G2 + k0 + quad * 8);
    for (int mt = 0; mt < 2; ++mt)
      for (int nt = 0; nt < 4; ++nt)
        acc[mt][nt] = mfma16(a[mt], bfr[nt], acc[mt][nt]);
  }
  for (int mt = 0; mt < 2; ++mt)
    for (int nt = 0; nt < 4; ++nt)
      for (int r = 0; r < 4; ++r) {
        int row = wave * 32 + mt * 16 + quad * 4 + r;
        int col = nt * 16 + nl;
        float v = acc[mt][nt][r] + bf2fs(T2[(size_t)row * NE + col]);
        Hp[(size_t)row * Kk + col] = f2bfs(fmaxf(v, 0.f));
      }
}

// ---------------- K7: out = Wh @ H^T + residual ------------------------------
__global__ void k_outgemm(const short* __restrict__ whb, const short* __restrict__ h,
                          const float* __restrict__ txt, const float* __restrict__ aud,
                          const float* __restrict__ vis, float* __restrict__ outp) {
  int s0 = blockIdx.x * 128, b = blockIdx.y, mod = blockIdx.z;
  const short* Wp = whb + (size_t)mod * Ss * Kk;
  const short* Hp = h + ((size_t)mod * Bb + b) * Ff * Kk;
  const float* xres = ((mod == 0) ? aud : (mod == 1) ? vis : txt) + (size_t)b * Ss * Ff;
  int slot = (mod == 0) ? 1 : (mod == 1) ? 2 : 0;   // output order (t, a, v)
  float* Op = outp + ((size_t)slot * Bb + b) * Ss * Ff;
  int tid = threadIdx.x, lane = tid & 63, wave = tid >> 6;
  int quad = lane >> 4, nl = lane & 15;
  int wm = (wave >> 1) * 64, wn = (wave & 1) * 64;
  facc zero = {0.f, 0.f, 0.f, 0.f};
  facc acc[4][4];
  for (int i = 0; i < 4; ++i) for (int j = 0; j < 4; ++j) acc[i][j] = zero;
  for (int k0 = 0; k0 < Kk; k0 += 32) {
    bfrag a[4], bfr[4];
    for (int mt = 0; mt < 4; ++mt)
      a[mt] = *(const bfrag*)(Wp + (size_t)(s0 + wm + mt * 16 + nl) * Kk + k0 + quad * 8);
    for (int nt = 0; nt < 4; ++nt)
      bfr[nt] = *(const bfrag*)(Hp + (size_t)(wn + nt * 16 + nl) * Kk + k0 + quad * 8);
    for (int mt = 0; mt < 4; ++mt)
      for (int nt = 0; nt < 4; ++nt)
        acc[mt][nt] = mfma16(a[mt], bfr[nt], acc[mt][nt]);
  }
  for (int mt = 0; mt < 4; ++mt)
    for (int nt = 0; nt < 4; ++nt)
      for (int r = 0; r < 4; ++r) {
        int srow = s0 + wm + mt * 16 + quad * 4 + r;
        int col = wn + nt * 16 + nl;
        size_t o = (size_t)srow * Ff + col;
        Op[o] = acc[mt][nt][r] + xres[o];
      }
}

extern "C" void kernel_launch(void* const* d_in, const int* in_sizes, int n_in,
                              void* d_out, int out_size, void* d_ws, size_t ws_size,
                              hipStream_t stream) {
  const float* txt = (const float*)d_in[0];
  const float* aud = (const float*)d_in[1];
  const float* vis = (const float*)d_in[2];
  const float* Wi  = (const float*)d_in[3];
  const float* bi  = (const float*)d_in[4];
  const float* Wq  = (const float*)d_in[5];
  const float* bq  = (const float*)d_in[6];
  const float* Wvp = (const float*)d_in[7];
  const float* bvp = (const float*)d_in[8];
  const float* Aa  = (const float*)d_in[9];
  const float* Av  = (const float*)d_in[10];
  const float* Al  = (const float*)d_in[11];
  const float* Wa  = (const float*)d_in[12];
  const float* Wv  = (const float*)d_in[13];
  const float* Wt  = (const float*)d_in[14];
  const float* Wca = (const float*)d_in[15];
  const float* Wcv = (const float*)d_in[16];
  const float* Wct = (const float*)d_in[17];
  const float* Wha = (const float*)d_in[18];
  const float* Whv = (const float*)d_in[19];
  const float* Wht = (const float*)d_in[20];

  char* w = (char*)d_ws;
  float* sumsq  = (float*)w;                    // 3 floats
  float* colnsq = (float*)(w + 256);            // B*F floats
  size_t off = 65536;
  short* xT   = (short*)(w + off); off += (size_t)3 * Bb * Ff * Ss * 2;   // 48MB
  short* aext = (short*)(w + off); off += (size_t)3 * Ss * NE * 2;        // 6.75MB
  short* g    = (short*)(w + off); off += (size_t)Bb * Ss * Ff * 2;       // 16MB
  short* mx   = (short*)(w + off);                                        // 56.6MB
  short* p1   = mx;                              // p1/p2 overlaid under mx:
  short* p2   = mx + (size_t)Bb * Ss * Ff;       // dead before k_mgemm writes
  off += (size_t)3 * Bb * Ff * NE * 2;
  short* cc   = (short*)(w + off); off += (size_t)3 * Bb * Ff * G2 * 2;   // 12MB
  short* h    = (short*)(w + off); off += (size_t)3 * Bb * Ff * Kk * 2;   // 3MB
  short* wcb  = (short*)(w + off); off += (size_t)3 * Kk * G2 * 2;
  short* whb  = (short*)(w + off); off += (size_t)3 * Ss * Kk * 2;

  hipMemsetAsync(d_ws, 0, 65536, stream);   // zero sumsq + colnsq (ws is re-poisoned)
  k_transpose<<<dim3(16, 2, 192), 256, 0, stream>>>(aud, vis, txt, xT);
  k_build_aext<<<(3 * Ss * NE) / 256, 256, 0, stream>>>(Aa, Av, Al, Wa, Wv, Wt, aext);
  k_build_w<<<(3 * Kk * G2 + 3 * Ss * Kk) / 256, 256, 0, stream>>>(Wca, Wcv, Wct,
                                                                   Wha, Whv, Wht, wcb, whb);
  k_amlp<<<dim3(Bb * Ss / 64, 3), 256, 0, stream>>>(txt, aud, vis, Wi, bi, Wq, bq,
                                                    Wvp, bvp, p1, p2, sumsq);
  k_colnorm<<<dim3(Bb, 16), 128, 0, stream>>>(p1, p2, sumsq, colnsq);
  k_gnorm<<<(Bb * Ss * Ff / 4) / 256, 256, 0, stream>>>(p1, p2, sumsq, colnsq, g);
  k_mgemm<<<dim3(Bb * Ff / 128, NE / 128, 3), 256, 0, stream>>>(xT, aext, mx);
  k_cgemm<<<dim3(Bb, 2, 3), 256, 0, stream>>>(mx, txt, aud, g, cc);
  k_hgemm<<<dim3(Bb, 3), 256, 0, stream>>>(cc, wcb, mx, h);
  k_outgemm<<<dim3(Ss / 128, Bb, 3), 256, 0, stream>>>(whb, h, txt, aud, vis, (float*)d_out);
}

// Round 2
// 482.776 us; speedup vs baseline: 1.6269x; 1.6269x over previous
//
#include <hip/hip_runtime.h>
#include <math.h>

constexpr int Bb = 64;
constexpr int Ss = 1024;
constexpr int Ff = 128;
constexpr int G2 = 256;   // 2F
constexpr int Kk = 64;
constexpr int NE = 1152;  // S + 64 (W^T cols) + 64 pad

typedef __bf16 bfrag __attribute__((ext_vector_type(8)));
typedef float  facc  __attribute__((ext_vector_type(4)));
typedef short  s8v   __attribute__((ext_vector_type(8)));

__device__ __forceinline__ short f2bfs(float f) {
  union { float f; unsigned u; } v; v.f = f;
  unsigned r = v.u + 0x7FFFu + ((v.u >> 16) & 1u);
  return (short)(r >> 16);
}
__device__ __forceinline__ float bf2fs(short s) {
  union { unsigned u; float f; } v; v.u = ((unsigned)(unsigned short)s) << 16;
  return v.f;
}
__device__ __forceinline__ facc mfma16(bfrag a, bfrag b, facc c) {
  return __builtin_amdgcn_mfma_f32_16x16x32_bf16(a, b, c, 0, 0, 0);
}

// ---------------- K0a: transpose+convert x -> xT bf16 [3][B][F][S] ------------
__global__ void k_transpose(const float* __restrict__ aud, const float* __restrict__ vis,
                            const float* __restrict__ txt, short* __restrict__ xT) {
  __shared__ float tile[64][65];
  int z = blockIdx.z;                 // mod*B + b
  int mod = z >> 6, b = z & 63;
  const float* x = (mod == 0) ? aud : (mod == 1) ? vis : txt;
  int s0 = blockIdx.x * 64, f0 = blockIdx.y * 64;
  int tid = threadIdx.x;
  for (int i = 0; i < 16; ++i) {
    int idx = i * 256 + tid;
    int si = idx >> 6, fi = idx & 63;
    tile[si][fi] = x[((size_t)b * Ss + s0 + si) * Ff + f0 + fi];
  }
  __syncthreads();
  short* dst = xT + ((size_t)mod * Bb + b) * Ff * Ss;
  for (int i = 0; i < 16; ++i) {
    int idx = i * 256 + tid;
    int fi = idx >> 6, si = idx & 63;
    dst[(size_t)(f0 + fi) * Ss + s0 + si] = f2bfs(tile[si][fi]);
  }
}

// ---------------- K0b: build AextT bf16 [3][NE][S]; row n: (A^T | W | 0) -----
__global__ void k_build_aextT(const float* __restrict__ Aa, const float* __restrict__ Av,
                              const float* __restrict__ Al, const float* __restrict__ Wa,
                              const float* __restrict__ Wv, const float* __restrict__ Wt,
                              short* __restrict__ aextT) {
  __shared__ float tile[64][65];
  int mod = blockIdx.z;
  const float* A = (mod == 0) ? Aa : (mod == 1) ? Av : Al;
  const float* W = (mod == 0) ? Wa : (mod == 1) ? Wv : Wt;
  short* dst = aextT + (size_t)mod * NE * Ss;
  int n0 = blockIdx.x * 64, t0 = blockIdx.y * 64;
  int tid = threadIdx.x;
  if (n0 < Ss) {
    for (int i = 0; i < 16; ++i) {
      int idx = i * 256 + tid;
      int ti = idx >> 6, nj = idx & 63;
      tile[ti][nj] = A[(size_t)(t0 + ti) * Ss + n0 + nj];
    }
    __syncthreads();
    for (int i = 0; i < 16; ++i) {
      int idx = i * 256 + tid;
      int nj = idx >> 6, ti = idx & 63;
      dst[(size_t)(n0 + nj) * Ss + t0 + ti] = f2bfs(tile[ti][nj]);
    }
  } else if (n0 < Ss + Kk) {
    for (int i = 0; i < 16; ++i) {
      int idx = i * 256 + tid;
      int j = idx >> 6, tt = idx & 63;
      dst[(size_t)(n0 + j) * Ss + t0 + tt] = f2bfs(W[(size_t)(n0 - Ss + j) * Ss + t0 + tt]);
    }
  } else {
    for (int i = 0; i < 16; ++i) {
      int idx = i * 256 + tid;
      int j = idx >> 6, tt = idx & 63;
      dst[(size_t)(n0 + j) * Ss + t0 + tt] = 0;
    }
  }
}

// ---------------- K0c: convert Wc, Wh; arrange AMLP W into LDS frag layout ----
__global__ void k_build_w(const float* __restrict__ Wca, const float* __restrict__ Wcv,
                          const float* __restrict__ Wct, const float* __restrict__ Wha,
                          const float* __restrict__ Whv, const float* __restrict__ Wht,
                          const float* __restrict__ Wi, const float* __restrict__ Wq,
                          const float* __restrict__ Wvp,
                          short* __restrict__ wcb, short* __restrict__ whb,
                          short* __restrict__ wbar) {
  int idx = blockIdx.x * 256 + threadIdx.x;
  const int n1 = 3 * Kk * G2;                // 49152
  const int n2 = n1 + 3 * Ss * Kk;           // 245760
  if (idx < n1) {
    int mod = idx / (Kk * G2), r = idx - mod * (Kk * G2);
    const float* W = (mod == 0) ? Wca : (mod == 1) ? Wcv : Wct;
    wcb[idx] = f2bfs(W[r]);
  } else if (idx < n2) {
    int j = idx - n1;
    int mod = j / (Ss * Kk), r = j - mod * (Ss * Kk);
    const float* W = (mod == 0) ? Wha : (mod == 1) ? Whv : Wht;
    whb[j] = f2bfs(W[r]);
  } else {
    int j = idx - n2;                        // < 3*G2*Ff
    int mod = j / (G2 * Ff), r = j - mod * (G2 * Ff);
    int n = r >> 7, k = r & 127;
    const float* W = (mod == 0) ? Wi : (mod == 1) ? Wq : Wvp;
    // layout: [(k>>3)][n][k&7] — fragment-contiguous 16B reads in k_amlp
    wbar[mod * G2 * Ff + (((k >> 3) * G2 + n) * 8) + (k & 7)] = f2bfs(W[r]);
  }
}

// ---------------- K1: AMLP f-GEMM, pooled p out + global sum(f^2) -------------
__global__ void __launch_bounds__(256) k_amlp(
    const float* __restrict__ txt, const float* __restrict__ aud, const float* __restrict__ vis,
    const float* __restrict__ bi, const float* __restrict__ bq, const float* __restrict__ bvp,
    const short* __restrict__ wbar,
    short* __restrict__ p1, short* __restrict__ p2, float* __restrict__ sumsq) {
  int mod = blockIdx.y;
  const float* x    = (mod == 0) ? txt : (mod == 1) ? aud : vis;
  const float* bias = (mod == 0) ? bi  : (mod == 1) ? bq  : bvp;
  const short* wbm  = wbar + mod * G2 * Ff;
  short* pout = (mod == 0) ? p1 : (mod == 1) ? p2 : nullptr;

  __shared__ short wlds[G2 * Ff];   // 64KB, pre-arranged layout
  __shared__ float wred[4];
  int tid = threadIdx.x, lane = tid & 63, wave = tid >> 6;
  int quad = lane >> 4, nl = lane & 15;
  for (int i = 0; i < 16; ++i) {     // linear conflict-free copy
    int o = (i * 256 + tid) * 8;
    *(s8v*)(wlds + o) = *(const s8v*)(wbm + o);
  }
  __syncthreads();

  int arow = blockIdx.x * 64 + wave * 16 + nl;     // A-operand row (m = lane&15)
  const float* xrow = x + (size_t)arow * Ff;
  facc zero = {0.f, 0.f, 0.f, 0.f};
  facc acc[16];
  for (int t = 0; t < 16; ++t) acc[t] = zero;
  for (int k0 = 0; k0 < Ff; k0 += 32) {
    float4 a0 = *(const float4*)(xrow + k0 + quad * 8);
    float4 a1 = *(const float4*)(xrow + k0 + quad * 8 + 4);
    bfrag af;
    af[0]=(__bf16)a0.x; af[1]=(__bf16)a0.y; af[2]=(__bf16)a0.z; af[3]=(__bf16)a0.w;
    af[4]=(__bf16)a1.x; af[5]=(__bf16)a1.y; af[6]=(__bf16)a1.z; af[7]=(__bf16)a1.w;
    int chunk = (k0 >> 3) + quad;
    for (int t = 0; t < 16; ++t) {
      bfrag bfr = *(const bfrag*)(wlds + ((size_t)chunk * G2 + t * 16 + nl) * 8);
      acc[t] = mfma16(af, bfr, acc[t]);
    }
  }

  float sq = 0.f;
  int drow = blockIdx.x * 64 + wave * 16 + quad * 4;  // D row base (m = quad*4+r)
  for (int t = 0; t < 16; ++t) {
    float bia = bias[t * 16 + nl];
    for (int r = 0; r < 4; ++r) {
      float fv = acc[t][r] + bia;
      sq += fv * fv;
      if (pout) {
        float fo = fv + __shfl_xor(fv, 1, 64);       // pair-pool along n
        if ((lane & 1) == 0)
          pout[(size_t)(drow + r) * Ff + t * 8 + (nl >> 1)] = f2bfs(fo);
      }
    }
  }
  for (int off = 32; off > 0; off >>= 1) sq += __shfl_down(sq, off, 64);
  if (lane == 0) wred[wave] = sq;
  __syncthreads();
  if (tid == 0) atomicAdd(&sumsq[mod], wred[0] + wred[1] + wred[2] + wred[3]);
}

// ---------------- K2: column norms over s of z -------------------------------
__global__ void k_colnorm(const short* __restrict__ p1, const short* __restrict__ p2,
                          const float* __restrict__ sumsq, float* __restrict__ colnsq) {
  float n1 = sqrtf(sumsq[0]), n2 = sqrtf(sumsq[1]), n3 = sqrtf(sumsq[2]);
  float w1 = n1 / (n1 + n2), w2 = n2 / (n1 + n2);
  float tc = 2.f * n3 * n3 / (n1 + n2 + n3);
  int b = blockIdx.x, j = threadIdx.x;
  int s0 = blockIdx.y * 64;
  float a = 0.f;
  for (int s = s0; s < s0 + 64; ++s) {
    size_t off = ((size_t)b * Ss + s) * Ff + j;
    float z = w1 * bf2fs(p1[off]) + w2 * bf2fs(p2[off]) + tc;
    a += z * z;
  }
  atomicAdd(&colnsq[b * Ff + j], a);
}

// ---------------- K3: gT[b][f][s] = z / max(colnorm,1e-12), tiled transpose ---
__global__ void k_gnormT(const short* __restrict__ p1, const short* __restrict__ p2,
                         const float* __restrict__ sumsq, const float* __restrict__ colnsq,
                         short* __restrict__ gT) {
  __shared__ float tile[64][65];
  float n1 = sqrtf(sumsq[0]), n2 = sqrtf(sumsq[1]), n3 = sqrtf(sumsq[2]);
  float w1 = n1 / (n1 + n2), w2 = n2 / (n1 + n2);
  float tc = 2.f * n3 * n3 / (n1 + n2 + n3);
  int b = blockIdx.z, s0 = blockIdx.x * 64, f0 = blockIdx.y * 64;
  int tid = threadIdx.x;
  for (int i = 0; i < 16; ++i) {
    int idx = i * 256 + tid;
    int si = idx >> 6, fi = idx & 63;
    size_t off = ((size_t)b * Ss + s0 + si) * Ff + f0 + fi;
    float z = w1 * bf2fs(p1[off]) + w2 * bf2fs(p2[off]) + tc;
    float cn = fmaxf(sqrtf(colnsq[b * Ff + f0 + fi]), 1e-12f);
    tile[si][fi] = z / cn;
  }
  __syncthreads();
  short* dst = gT + (size_t)b * Ff * Ss;
  for (int i = 0; i < 16; ++i) {
    int idx = i * 256 + tid;
    int fi = idx >> 6, si = idx & 63;
    dst[(size_t)(f0 + fi) * Ss + s0 + si] = f2bfs(tile[si][fi]);
  }
}

// ---------------- K4: M-GEMM  [8192,1024]x[1024,1152]^T per modality ---------
__global__ void __launch_bounds__(256) k_mgemm(const short* __restrict__ xT,
                                               const short* __restrict__ aextT,
                                               short* __restrict__ mxext) {
  int mod = blockIdx.z;
  const short* Ap = xT + (size_t)mod * Bb * Ff * Ss;
  const short* Bp = aextT + (size_t)mod * NE * Ss;
  short* Op = mxext + (size_t)mod * Bb * Ff * NE;
  int M0 = blockIdx.x * 128, N0 = blockIdx.y * 128;
  __shared__ short As[128 * 32];
  __shared__ short Bs[128 * 32];
  int tid = threadIdx.x, lane = tid & 63, wave = tid >> 6;
  int quad = lane >> 4, nl = lane & 15;
  int wm = (wave >> 1) * 64, wn = (wave & 1) * 64;
  int r0 = tid >> 2, c8 = (tid & 3) * 8;
  facc zero = {0.f, 0.f, 0.f, 0.f};
  facc acc[4][4];
  for (int i = 0; i < 4; ++i) for (int j = 0; j < 4; ++j) acc[i][j] = zero;
  for (int k0 = 0; k0 < Ss; k0 += 32) {
    __syncthreads();
    // straight row copies: conflict-free b128 writes (As flat off == tid*8)
    *(s8v*)(As + tid * 8)        = *(const s8v*)(Ap + (size_t)(M0 + r0) * Ss + k0 + c8);
    *(s8v*)(As + 2048 + tid * 8) = *(const s8v*)(Ap + (size_t)(M0 + 64 + r0) * Ss + k0 + c8);
    *(s8v*)(Bs + tid * 8)        = *(const s8v*)(Bp + (size_t)(N0 + r0) * Ss + k0 + c8);
    *(s8v*)(Bs + 2048 + tid * 8) = *(const s8v*)(Bp + (size_t)(N0 + 64 + r0) * Ss + k0 + c8);
    __syncthreads();
    bfrag a[4], bfr[4];
    for (int mt = 0; mt < 4; ++mt)
      a[mt] = *(const bfrag*)(As + (wm + mt * 16 + nl) * 32 + quad * 8);
    for (int nt = 0; nt < 4; ++nt)
      bfr[nt] = *(const bfrag*)(Bs + (wn + nt * 16 + nl) * 32 + quad * 8);
    for (int mt = 0; mt < 4; ++mt)
      for (int nt = 0; nt < 4; ++nt)
        acc[mt][nt] = mfma16(a[mt], bfr[nt], acc[mt][nt]);
  }
  for (int mt = 0; mt < 4; ++mt)
    for (int nt = 0; nt < 4; ++nt)
      for (int r = 0; r < 4; ++r) {
        int row = M0 + wm + mt * 16 + quad * 4 + r;
        int col = N0 + wn + nt * 16 + nl;
        Op[(size_t)row * NE + col] = f2bfs(acc[mt][nt][r]);
      }
}

// ---------------- K5: C-GEMM  C = tanh((M @ [x|G])/16) -----------------------
__global__ void __launch_bounds__(256) k_cgemm(const short* __restrict__ mxext,
                                               const short* __restrict__ xT,
                                               const short* __restrict__ gT,
                                               short* __restrict__ cc) {
  int b = blockIdx.x, half = blockIdx.y, mod = blockIdx.z;
  const short* Ap = mxext + ((size_t)mod * Bb + b) * Ff * NE;
  // modality a and v both use aud (= xT slot 0, source bug); t uses txt (slot 2)
  const short* Bsrc = (half == 0)
      ? (xT + (size_t)((mod == 2) ? 2 : 0) * Bb * Ff * Ss + (size_t)b * Ff * Ss)
      : (gT + (size_t)b * Ff * Ss);
  short* Cp = cc + ((size_t)mod * Bb + b) * Ff * G2;
  __shared__ short As[128 * 32];
  __shared__ short Bs[128 * 32];
  int tid = threadIdx.x, lane = tid & 63, wave = tid >> 6;
  int quad = lane >> 4, nl = lane & 15;
  int wm = (wave >> 1) * 64, wn = (wave & 1) * 64;
  int r0 = tid >> 2, c8 = (tid & 3) * 8;
  facc zero = {0.f, 0.f, 0.f, 0.f};
  facc acc[4][4];
  for (int i = 0; i < 4; ++i) for (int j = 0; j < 4; ++j) acc[i][j] = zero;
  for (int k0 = 0; k0 < Ss; k0 += 32) {
    __syncthreads();
    *(s8v*)(As + tid * 8)        = *(const s8v*)(Ap + (size_t)r0 * NE + k0 + c8);
    *(s8v*)(As + 2048 + tid * 8) = *(const s8v*)(Ap + (size_t)(64 + r0) * NE + k0 + c8);
    *(s8v*)(Bs + tid * 8)        = *(const s8v*)(Bsrc + (size_t)r0 * Ss + k0 + c8);
    *(s8v*)(Bs + 2048 + tid * 8) = *(const s8v*)(Bsrc + (size_t)(64 + r0) * Ss + k0 + c8);
    __syncthreads();
    bfrag a[4], bfr[4];
    for (int mt = 0; mt < 4; ++mt)
      a[mt] = *(const bfrag*)(As + (wm + mt * 16 + nl) * 32 + quad * 8);
    for (int nt = 0; nt < 4; ++nt)
      bfr[nt] = *(const bfrag*)(Bs + (wn + nt * 16 + nl) * 32 + quad * 8);
    for (int mt = 0; mt < 4; ++mt)
      for (int nt = 0; nt < 4; ++nt)
        acc[mt][nt] = mfma16(a[mt], bfr[nt], acc[mt][nt]);
  }
  for (int mt = 0; mt < 4; ++mt)
    for (int nt = 0; nt < 4; ++nt)
      for (int r = 0; r < 4; ++r) {
        int row = wm + mt * 16 + quad * 4 + r;
        int col = half * 128 + wn + nt * 16 + nl;
        Cp[(size_t)row * G2 + col] = f2bfs(tanhf(acc[mt][nt][r] * 0.0625f));
      }
}

// ---------------- K6: H = relu(C @ Wc^T + T2) --------------------------------
__global__ void k_hgemm(const short* __restrict__ cc, const short* __restrict__ wcb,
                        const short* __restrict__ mxext, short* __restrict__ h) {
  int b = blockIdx.x, mod = blockIdx.y;
  const short* Cp = cc + ((size_t)mod * Bb + b) * Ff * G2;
  const short* Wp = wcb + (size_t)mod * Kk * G2;
  const short* T2 = mxext + ((size_t)mod * Bb + b) * Ff * NE + Ss;
  short* Hp = h + ((size_t)mod * Bb + b) * Ff * Kk;
  int tid = threadIdx.x, lane = tid & 63, wave = tid >> 6;
  int quad = lane >> 4, nl = lane & 15;
  facc zero = {0.f, 0.f, 0.f, 0.f};
  facc acc[2][4];
  for (int i = 0; i < 2; ++i) for (int j = 0; j < 4; ++j) acc[i][j] = zero;
  for (int k0 = 0; k0 < G2; k0 += 32) {
    bfrag a[2], bfr[4];
    for (int mt = 0; mt < 2; ++mt)
      a[mt] = *(const bfrag*)(Cp + (size_t)(wave * 32 + mt * 16 + nl) * G2 + k0 + quad * 8);
    for (int nt = 0; nt < 4; ++nt)
      bfr[nt] = *(const bfrag*)(Wp + (size_t)(nt * 16 + nl) * G2 + k0 + quad * 8);
    for (int mt = 0; mt < 2; ++mt)
      for (int nt = 0; nt < 4; ++nt)
        acc[mt][nt] = mfma16(a[mt], bfr[nt], acc[mt][nt]);
  }
  for (int mt = 0; mt < 2; ++mt)
    for (int nt = 0; nt < 4; ++nt)
      for (int r = 0; r < 4; ++r) {
        int row = wave * 32 + mt * 16 + quad * 4 + r;
        int col = nt * 16 + nl;
        float v = acc[mt][nt][r] + bf2fs(T2[(size_t)row * NE + col]);
        Hp[(size_t)row * Kk + col] = f2bfs(fmaxf(v, 0.f));
      }
}

// ---------------- K7: out = Wh @ H^T + residual ------------------------------
__global__ void k_outgemm(const short* __restrict__ whb, const short* __restrict__ h,
                          const float* __restrict__ txt, const float* __restrict__ aud,
                          const float* __restrict__ vis, float* __restrict__ outp) {
  int s0 = blockIdx.x * 128, b = blockIdx.y, mod = blockIdx.z;
  const short* Wp = whb + (size_t)mod * Ss * Kk;
  const short* Hp = h + ((size_t)mod * Bb + b) * Ff * Kk;
  const float* xres = ((mod == 0) ? aud : (mod == 1) ? vis : txt) + (size_t)b * Ss * Ff;
  int slot = (mod == 0) ? 1 : (mod == 1) ? 2 : 0;   // output order (t, a, v)
  float* Op = outp + ((size_t)slot * Bb + b) * Ss * Ff;
  int tid = threadIdx.x, lane = tid & 63, wave = tid >> 6;
  int quad = lane >> 4, nl = lane & 15;
  int wm = (wave >> 1) * 64, wn = (wave & 1) * 64;
  facc zero = {0.f, 0.f, 0.f, 0.f};
  facc acc[4][4];
  for (int i = 0; i < 4; ++i) for (int j = 0; j < 4; ++j) acc[i][j] = zero;
  for (int k0 = 0; k0 < Kk; k0 += 32) {
    bfrag a[4], bfr[4];
    for (int mt = 0; mt < 4; ++mt)
      a[mt] = *(const bfrag*)(Wp + (size_t)(s0 + wm + mt * 16 + nl) * Kk + k0 + quad * 8);
    for (int nt = 0; nt < 4; ++nt)
      bfr[nt] = *(const bfrag*)(Hp + (size_t)(wn + nt * 16 + nl) * Kk + k0 + quad * 8);
    for (int mt = 0; mt < 4; ++mt)
      for (int nt = 0; nt < 4; ++nt)
        acc[mt][nt] = mfma16(a[mt], bfr[nt], acc[mt][nt]);
  }
  for (int mt = 0; mt < 4; ++mt)
    for (int nt = 0; nt < 4; ++nt)
      for (int r = 0; r < 4; ++r) {
        int srow = s0 + wm + mt * 16 + quad * 4 + r;
        int col = wn + nt * 16 + nl;
        size_t o = (size_t)srow * Ff + col;
        Op[o] = acc[mt][nt][r] + xres[o];
      }
}

extern "C" void kernel_launch(void* const* d_in, const int* in_sizes, int n_in,
                              void* d_out, int out_size, void* d_ws, size_t ws_size,
                              hipStream_t stream) {
  const float* txt = (const float*)d_in[0];
  const float* aud = (const float*)d_in[1];
  const float* vis = (const float*)d_in[2];
  const float* Wi  = (const float*)d_in[3];
  const float* bi  = (const float*)d_in[4];
  const float* Wq  = (const float*)d_in[5];
  const float* bq  = (const float*)d_in[6];
  const float* Wvp = (const float*)d_in[7];
  const float* bvp = (const float*)d_in[8];
  const float* Aa  = (const float*)d_in[9];
  const float* Av  = (const float*)d_in[10];
  const float* Al  = (const float*)d_in[11];
  const float* Wa  = (const float*)d_in[12];
  const float* Wv  = (const float*)d_in[13];
  const float* Wt  = (const float*)d_in[14];
  const float* Wca = (const float*)d_in[15];
  const float* Wcv = (const float*)d_in[16];
  const float* Wct = (const float*)d_in[17];
  const float* Wha = (const float*)d_in[18];
  const float* Whv = (const float*)d_in[19];
  const float* Wht = (const float*)d_in[20];

  char* w = (char*)d_ws;
  float* sumsq  = (float*)w;                    // 3 floats
  float* colnsq = (float*)(w + 256);            // B*F floats
  size_t off = 65536;
  short* xT    = (short*)(w + off); off += (size_t)3 * Bb * Ff * Ss * 2;   // 48MB
  short* aextT = (short*)(w + off); off += (size_t)3 * NE * Ss * 2;        // 6.75MB
  short* gT    = (short*)(w + off); off += (size_t)Bb * Ff * Ss * 2;       // 16MB
  short* mx    = (short*)(w + off);                                        // 54MB
  short* p1    = mx;                             // p1/p2 overlaid under mx:
  short* p2    = mx + (size_t)Bb * Ss * Ff;      // dead before k_mgemm writes
  off += (size_t)3 * Bb * Ff * NE * 2;
  short* cc    = (short*)(w + off); off += (size_t)3 * Bb * Ff * G2 * 2;   // 12MB
  short* h     = (short*)(w + off); off += (size_t)3 * Bb * Ff * Kk * 2;   // 3MB
  short* wcb   = (short*)(w + off); off += (size_t)3 * Kk * G2 * 2;
  short* whb   = (short*)(w + off); off += (size_t)3 * Ss * Kk * 2;
  short* wbar  = (short*)(w + off); off += (size_t)3 * G2 * Ff * 2;

  hipMemsetAsync(d_ws, 0, 65536, stream);   // zero sumsq + colnsq
  k_transpose<<<dim3(16, 2, 192), 256, 0, stream>>>(aud, vis, txt, xT);
  k_build_aextT<<<dim3(NE / 64, 16, 3), 256, 0, stream>>>(Aa, Av, Al, Wa, Wv, Wt, aextT);
  k_build_w<<<(3 * Kk * G2 + 3 * Ss * Kk + 3 * G2 * Ff) / 256, 256, 0, stream>>>(
      Wca, Wcv, Wct, Wha, Whv, Wht, Wi, Wq, Wvp, wcb, whb, wbar);
  k_amlp<<<dim3(Bb * Ss / 64, 3), 256, 0, stream>>>(txt, aud, vis, bi, bq, bvp,
                                                    wbar, p1, p2, sumsq);
  k_colnorm<<<dim3(Bb, 16), 128, 0, stream>>>(p1, p2, sumsq, colnsq);
  k_gnormT<<<dim3(16, 2, Bb), 256, 0, stream>>>(p1, p2, sumsq, colnsq, gT);
  k_mgemm<<<dim3(Bb * Ff / 128, NE / 128, 3), 256, 0, stream>>>(xT, aextT, mx);
  k_cgemm<<<dim3(Bb, 2, 3), 256, 0, stream>>>(mx, xT, gT, cc);
  k_hgemm<<<dim3(Bb, 3), 256, 0, stream>>>(cc, wcb, mx, h);
  k_outgemm<<<dim3(Ss / 128, Bb, 3), 256, 0, stream>>>(whb, h, txt, aud, vis, (float*)d_out);
}

// Round 3
// 478.180 us; speedup vs baseline: 1.6425x; 1.0096x over previous
//
#include <hip/hip_runtime.h>
#include <math.h>

constexpr int Bb = 64;
constexpr int Ss = 1024;
constexpr int Ff = 128;
constexpr int G2 = 256;   // 2F
constexpr int Kk = 64;
constexpr int NE = 1152;  // S + 64 (W^T cols) + 64 pad

typedef __bf16 bfrag __attribute__((ext_vector_type(8)));
typedef float  facc  __attribute__((ext_vector_type(4)));
typedef short  s8v   __attribute__((ext_vector_type(8)));

__device__ __forceinline__ short f2bfs(float f) {
  union { float f; unsigned u; } v; v.f = f;
  unsigned r = v.u + 0x7FFFu + ((v.u >> 16) & 1u);
  return (short)(r >> 16);
}
__device__ __forceinline__ float bf2fs(short s) {
  union { unsigned u; float f; } v; v.u = ((unsigned)(unsigned short)s) << 16;
  return v.f;
}
__device__ __forceinline__ facc mfma16(bfrag a, bfrag b, facc c) {
  return __builtin_amdgcn_mfma_f32_16x16x32_bf16(a, b, c, 0, 0, 0);
}
// async global->LDS, 16B per lane; LDS dest must be wave-uniform base + lane*16
__device__ __forceinline__ void gld16(const void* g, void* l) {
  __builtin_amdgcn_global_load_lds(
      (const __attribute__((address_space(1))) void*)g,
      (__attribute__((address_space(3))) void*)l, 16, 0, 0);
}

// ---------------- K0a: transpose+convert x -> xT bf16 [3][B][F][S] ------------
__global__ void k_transpose(const float* __restrict__ aud, const float* __restrict__ vis,
                            const float* __restrict__ txt, short* __restrict__ xT) {
  __shared__ float tile[64][65];
  int z = blockIdx.z;                 // mod*B + b
  int mod = z >> 6, b = z & 63;
  const float* x = (mod == 0) ? aud : (mod == 1) ? vis : txt;
  int s0 = blockIdx.x * 64, f0 = blockIdx.y * 64;
  int tid = threadIdx.x;
  for (int i = 0; i < 16; ++i) {
    int idx = i * 256 + tid;
    int si = idx >> 6, fi = idx & 63;
    tile[si][fi] = x[((size_t)b * Ss + s0 + si) * Ff + f0 + fi];
  }
  __syncthreads();
  short* dst = xT + ((size_t)mod * Bb + b) * Ff * Ss;
  for (int i = 0; i < 16; ++i) {
    int idx = i * 256 + tid;
    int fi = idx >> 6, si = idx & 63;
    dst[(size_t)(f0 + fi) * Ss + s0 + si] = f2bfs(tile[si][fi]);
  }
}

// ---------------- K0b: build AextT bf16 [3][NE][S]; row n: (A^T | W | 0) -----
__global__ void k_build_aextT(const float* __restrict__ Aa, const float* __restrict__ Av,
                              const float* __restrict__ Al, const float* __restrict__ Wa,
                              const float* __restrict__ Wv, const float* __restrict__ Wt,
                              short* __restrict__ aextT) {
  __shared__ float tile[64][65];
  int mod = blockIdx.z;
  const float* A = (mod == 0) ? Aa : (mod == 1) ? Av : Al;
  const float* W = (mod == 0) ? Wa : (mod == 1) ? Wv : Wt;
  short* dst = aextT + (size_t)mod * NE * Ss;
  int n0 = blockIdx.x * 64, t0 = blockIdx.y * 64;
  int tid = threadIdx.x;
  if (n0 < Ss) {
    for (int i = 0; i < 16; ++i) {
      int idx = i * 256 + tid;
      int ti = idx >> 6, nj = idx & 63;
      tile[ti][nj] = A[(size_t)(t0 + ti) * Ss + n0 + nj];
    }
    __syncthreads();
    for (int i = 0; i < 16; ++i) {
      int idx = i * 256 + tid;
      int nj = idx >> 6, ti = idx & 63;
      dst[(size_t)(n0 + nj) * Ss + t0 + ti] = f2bfs(tile[ti][nj]);
    }
  } else if (n0 < Ss + Kk) {
    for (int i = 0; i < 16; ++i) {
      int idx = i * 256 + tid;
      int j = idx >> 6, tt = idx & 63;
      dst[(size_t)(n0 + j) * Ss + t0 + tt] = f2bfs(W[(size_t)(n0 - Ss + j) * Ss + t0 + tt]);
    }
  } else {
    for (int i = 0; i < 16; ++i) {
      int idx = i * 256 + tid;
      int j = idx >> 6, tt = idx & 63;
      dst[(size_t)(n0 + j) * Ss + t0 + tt] = 0;
    }
  }
}

// ---------------- K0c: convert Wc, Wh; arrange AMLP W into LDS frag layout ----
__global__ void k_build_w(const float* __restrict__ Wca, const float* __restrict__ Wcv,
                          const float* __restrict__ Wct, const float* __restrict__ Wha,
                          const float* __restrict__ Whv, const float* __restrict__ Wht,
                          const float* __restrict__ Wi, const float* __restrict__ Wq,
                          const float* __restrict__ Wvp,
                          short* __restrict__ wcb, short* __restrict__ whb,
                          short* __restrict__ wbar) {
  int idx = blockIdx.x * 256 + threadIdx.x;
  const int n1 = 3 * Kk * G2;                // 49152
  const int n2 = n1 + 3 * Ss * Kk;           // 245760
  if (idx < n1) {
    int mod = idx / (Kk * G2), r = idx - mod * (Kk * G2);
    const float* W = (mod == 0) ? Wca : (mod == 1) ? Wcv : Wct;
    wcb[idx] = f2bfs(W[r]);
  } else if (idx < n2) {
    int j = idx - n1;
    int mod = j / (Ss * Kk), r = j - mod * (Ss * Kk);
    const float* W = (mod == 0) ? Wha : (mod == 1) ? Whv : Wht;
    whb[j] = f2bfs(W[r]);
  } else {
    int j = idx - n2;                        // < 3*G2*Ff
    int mod = j / (G2 * Ff), r = j - mod * (G2 * Ff);
    int n = r >> 7, k = r & 127;
    const float* W = (mod == 0) ? Wi : (mod == 1) ? Wq : Wvp;
    // layout: [(k>>3)][n][k&7] — fragment-contiguous 16B reads in k_amlp
    wbar[mod * G2 * Ff + (((k >> 3) * G2 + n) * 8) + (k & 7)] = f2bfs(W[r]);
  }
}

// ---------------- K1: AMLP f-GEMM, pooled p out + global sum(f^2) -------------
// 256 rows per block (4 row-groups) to amortize the 64KB weight stage.
__global__ void __launch_bounds__(256) k_amlp(
    const float* __restrict__ txt, const float* __restrict__ aud, const float* __restrict__ vis,
    const float* __restrict__ bi, const float* __restrict__ bq, const float* __restrict__ bvp,
    const short* __restrict__ wbar,
    short* __restrict__ p1, short* __restrict__ p2, float* __restrict__ sumsq) {
  int mod = blockIdx.y;
  const float* x    = (mod == 0) ? txt : (mod == 1) ? aud : vis;
  const float* bias = (mod == 0) ? bi  : (mod == 1) ? bq  : bvp;
  const short* wbm  = wbar + mod * G2 * Ff;
  short* pout = (mod == 0) ? p1 : (mod == 1) ? p2 : nullptr;

  __shared__ short wlds[G2 * Ff];   // 64KB, pre-arranged layout
  __shared__ float wred[4];
  int tid = threadIdx.x, lane = tid & 63, wave = tid >> 6;
  int quad = lane >> 4, nl = lane & 15;
  for (int i = 0; i < 16; ++i) {     // async linear copy, dest = i*4096 + tid*16 bytes
    int o = (i * 256 + tid) * 8;
    gld16(wbm + o, wlds + o);
  }
  __syncthreads();

  float bia[16];
  for (int t = 0; t < 16; ++t) bia[t] = bias[t * 16 + nl];

  facc zero = {0.f, 0.f, 0.f, 0.f};
  float sq = 0.f;
  for (int rg = 0; rg < 4; ++rg) {
    int arow = blockIdx.x * 256 + rg * 64 + wave * 16 + nl;   // A row (m = lane&15)
    const float* xrow = x + (size_t)arow * Ff;
    facc acc[16];
    for (int t = 0; t < 16; ++t) acc[t] = zero;
    for (int k0 = 0; k0 < Ff; k0 += 32) {
      float4 a0 = *(const float4*)(xrow + k0 + quad * 8);
      float4 a1 = *(const float4*)(xrow + k0 + quad * 8 + 4);
      bfrag af;
      af[0]=(__bf16)a0.x; af[1]=(__bf16)a0.y; af[2]=(__bf16)a0.z; af[3]=(__bf16)a0.w;
      af[4]=(__bf16)a1.x; af[5]=(__bf16)a1.y; af[6]=(__bf16)a1.z; af[7]=(__bf16)a1.w;
      int chunk = (k0 >> 3) + quad;
      for (int t = 0; t < 16; ++t) {
        bfrag bfr = *(const bfrag*)(wlds + ((size_t)chunk * G2 + t * 16 + nl) * 8);
        acc[t] = mfma16(af, bfr, acc[t]);
      }
    }
    int drow = blockIdx.x * 256 + rg * 64 + wave * 16 + quad * 4;  // D row (m=quad*4+r)
    for (int t = 0; t < 16; ++t) {
      for (int r = 0; r < 4; ++r) {
        float fv = acc[t][r] + bia[t];
        sq += fv * fv;
        if (pout) {
          float fo = fv + __shfl_xor(fv, 1, 64);       // pair-pool along n
          if ((lane & 1) == 0)
            pout[(size_t)(drow + r) * Ff + t * 8 + (nl >> 1)] = f2bfs(fo);
        }
      }
    }
  }
  for (int off = 32; off > 0; off >>= 1) sq += __shfl_down(sq, off, 64);
  if (lane == 0) wred[wave] = sq;
  __syncthreads();
  if (tid == 0) atomicAdd(&sumsq[mod], wred[0] + wred[1] + wred[2] + wred[3]);
}

// ---------------- K2: column norms over s of z -------------------------------
__global__ void k_colnorm(const short* __restrict__ p1, const short* __restrict__ p2,
                          const float* __restrict__ sumsq, float* __restrict__ colnsq) {
  float n1 = sqrtf(sumsq[0]), n2 = sqrtf(sumsq[1]), n3 = sqrtf(sumsq[2]);
  float w1 = n1 / (n1 + n2), w2 = n2 / (n1 + n2);
  float tc = 2.f * n3 * n3 / (n1 + n2 + n3);
  int b = blockIdx.x, j = threadIdx.x;
  int s0 = blockIdx.y * 64;
  float a = 0.f;
  for (int s = s0; s < s0 + 64; ++s) {
    size_t off = ((size_t)b * Ss + s) * Ff + j;
    float z = w1 * bf2fs(p1[off]) + w2 * bf2fs(p2[off]) + tc;
    a += z * z;
  }
  atomicAdd(&colnsq[b * Ff + j], a);
}

// ---------------- K3: gT[b][f][s] = z / max(colnorm,1e-12), tiled transpose ---
__global__ void k_gnormT(const short* __restrict__ p1, const short* __restrict__ p2,
                         const float* __restrict__ sumsq, const float* __restrict__ colnsq,
                         short* __restrict__ gT) {
  __shared__ float tile[64][65];
  float n1 = sqrtf(sumsq[0]), n2 = sqrtf(sumsq[1]), n3 = sqrtf(sumsq[2]);
  float w1 = n1 / (n1 + n2), w2 = n2 / (n1 + n2);
  float tc = 2.f * n3 * n3 / (n1 + n2 + n3);
  int b = blockIdx.z, s0 = blockIdx.x * 64, f0 = blockIdx.y * 64;
  int tid = threadIdx.x;
  for (int i = 0; i < 16; ++i) {
    int idx = i * 256 + tid;
    int si = idx >> 6, fi = idx & 63;
    size_t off = ((size_t)b * Ss + s0 + si) * Ff + f0 + fi;
    float z = w1 * bf2fs(p1[off]) + w2 * bf2fs(p2[off]) + tc;
    float cn = fmaxf(sqrtf(colnsq[b * Ff + f0 + fi]), 1e-12f);
    tile[si][fi] = z / cn;
  }
  __syncthreads();
  short* dst = gT + (size_t)b * Ff * Ss;
  for (int i = 0; i < 16; ++i) {
    int idx = i * 256 + tid;
    int fi = idx >> 6, si = idx & 63;
    dst[(size_t)(f0 + fi) * Ss + s0 + si] = f2bfs(tile[si][fi]);
  }
}

// ---------------- K4: M-GEMM  [8192,1024]x[1024,1152]^T per modality ---------
__global__ void __launch_bounds__(256) k_mgemm(const short* __restrict__ xT,
                                               const short* __restrict__ aextT,
                                               short* __restrict__ mxext) {
  int mod = blockIdx.z;
  const short* Ap = xT + (size_t)mod * Bb * Ff * Ss;
  const short* Bp = aextT + (size_t)mod * NE * Ss;
  short* Op = mxext + (size_t)mod * Bb * Ff * NE;
  int M0 = blockIdx.x * 128, N0 = blockIdx.y * 128;
  __shared__ short As[128 * 32];
  __shared__ short Bs[128 * 32];
  int tid = threadIdx.x, lane = tid & 63, wave = tid >> 6;
  int quad = lane >> 4, nl = lane & 15;
  int wm = (wave >> 1) * 64, wn = (wave & 1) * 64;
  int r0 = tid >> 2, c8 = (tid & 3) * 8;
  facc zero = {0.f, 0.f, 0.f, 0.f};
  facc acc[4][4];
  for (int i = 0; i < 4; ++i) for (int j = 0; j < 4; ++j) acc[i][j] = zero;
  for (int k0 = 0; k0 < Ss; k0 += 32) {
    __syncthreads();
    // async global->LDS: dest byte == tid*16 (+4096), wave-uniform base + lane*16
    gld16(Ap + (size_t)(M0 + r0) * Ss + k0 + c8,      As + tid * 8);
    gld16(Ap + (size_t)(M0 + 64 + r0) * Ss + k0 + c8, As + 2048 + tid * 8);
    gld16(Bp + (size_t)(N0 + r0) * Ss + k0 + c8,      Bs + tid * 8);
    gld16(Bp + (size_t)(N0 + 64 + r0) * Ss + k0 + c8, Bs + 2048 + tid * 8);
    __syncthreads();
    bfrag a[4], bfr[4];
    for (int mt = 0; mt < 4; ++mt)
      a[mt] = *(const bfrag*)(As + (wm + mt * 16 + nl) * 32 + quad * 8);
    for (int nt = 0; nt < 4; ++nt)
      bfr[nt] = *(const bfrag*)(Bs + (wn + nt * 16 + nl) * 32 + quad * 8);
    for (int mt = 0; mt < 4; ++mt)
      for (int nt = 0; nt < 4; ++nt)
        acc[mt][nt] = mfma16(a[mt], bfr[nt], acc[mt][nt]);
  }
  for (int mt = 0; mt < 4; ++mt)
    for (int nt = 0; nt < 4; ++nt)
      for (int r = 0; r < 4; ++r) {
        int row = M0 + wm + mt * 16 + quad * 4 + r;
        int col = N0 + wn + nt * 16 + nl;
        Op[(size_t)row * NE + col] = f2bfs(acc[mt][nt][r]);
      }
}

// ---------------- K5: C-GEMM  C = tanh((M @ [x|G])/16), 128x64 tiles ---------
__global__ void __launch_bounds__(256) k_cgemm(const short* __restrict__ mxext,
                                               const short* __restrict__ xT,
                                               const short* __restrict__ gT,
                                               short* __restrict__ cc) {
  int b = blockIdx.x, nt4 = blockIdx.y, mod = blockIdx.z;   // nt4: 64-col tile of G2
  const short* Ap = mxext + ((size_t)mod * Bb + b) * Ff * NE;
  // cols 0..127 from x (a,v use aud = slot 0, source bug; t uses txt = slot 2);
  // cols 128..255 from G
  const short* Bsrc = (nt4 < 2)
      ? (xT + (size_t)((mod == 2) ? 2 : 0) * Bb * Ff * Ss + (size_t)b * Ff * Ss
             + (size_t)(nt4 & 1) * 64 * Ss)
      : (gT + (size_t)b * Ff * Ss + (size_t)(nt4 & 1) * 64 * Ss);
  short* Cp = cc + ((size_t)mod * Bb + b) * Ff * G2;
  int ncol0 = nt4 * 64;
  __shared__ short As[128 * 32];   // 8KB
  __shared__ short Bs[64 * 32];    // 4KB
  int tid = threadIdx.x, lane = tid & 63, wave = tid >> 6;
  int quad = lane >> 4, nl = lane & 15;
  int wm = (wave >> 1) * 64, wn = (wave & 1) * 32;
  int r0 = tid >> 2, c8 = (tid & 3) * 8;
  facc zero = {0.f, 0.f, 0.f, 0.f};
  facc acc[4][2];
  for (int i = 0; i < 4; ++i) for (int j = 0; j < 2; ++j) acc[i][j] = zero;
  for (int k0 = 0; k0 < Ss; k0 += 32) {
    __syncthreads();
    gld16(Ap + (size_t)r0 * NE + k0 + c8,        As + tid * 8);
    gld16(Ap + (size_t)(64 + r0) * NE + k0 + c8, As + 2048 + tid * 8);
    gld16(Bsrc + (size_t)r0 * Ss + k0 + c8,      Bs + tid * 8);
    __syncthreads();
    bfrag a[4], bfr[2];
    for (int mt = 0; mt < 4; ++mt)
      a[mt] = *(const bfrag*)(As + (wm + mt * 16 + nl) * 32 + quad * 8);
    for (int nt = 0; nt < 2; ++nt)
      bfr[nt] = *(const bfrag*)(Bs + (wn + nt * 16 + nl) * 32 + quad * 8);
    for (int mt = 0; mt < 4; ++mt)
      for (int nt = 0; nt < 2; ++nt)
        acc[mt][nt] = mfma16(a[mt], bfr[nt], acc[mt][nt]);
  }
  for (int mt = 0; mt < 4; ++mt)
    for (int nt = 0; nt < 2; ++nt)
      for (int r = 0; r < 4; ++r) {
        int row = wm + mt * 16 + quad * 4 + r;
        int col = ncol0 + wn + nt * 16 + nl;
        Cp[(size_t)row * G2 + col] = f2bfs(tanhf(acc[mt][nt][r] * 0.0625f));
      }
}

// ---------------- K6: H = relu(C @ Wc^T + T2) --------------------------------
__global__ void k_hgemm(const short* __restrict__ cc, const short* __restrict__ wcb,
                        const short* __restrict__ mxext, short* __restrict__ h) {
  int b = blockIdx.x, mod = blockIdx.y;
  const short* Cp = cc + ((size_t)mod * Bb + b) * Ff * G2;
  const short* Wp = wcb + (size_t)mod * Kk * G2;
  const short* T2 = mxext + ((size_t)mod * Bb + b) * Ff * NE + Ss;
  short* Hp = h + ((size_t)mod * Bb + b) * Ff * Kk;
  int tid = threadIdx.x, lane = tid & 63, wave = tid >> 6;
  int quad = lane >> 4, nl = lane & 15;
  facc zero = {0.f, 0.f, 0.f, 0.f};
  facc acc[2][4];
  for (int i = 0; i < 2; ++i) for (int j = 0; j < 4; ++j) acc[i][j] = zero;
  for (int k0 = 0; k0 < G2; k0 += 32) {
    bfrag a[2], bfr[4];
    for (int mt = 0; mt < 2; ++mt)
      a[mt] = *(const bfrag*)(Cp + (size_t)(wave * 32 + mt * 16 + nl) * G2 + k0 + quad * 8);
    for (int nt = 0; nt < 4; ++nt)
      bfr[nt] = *(const bfrag*)(Wp + (size_t)(nt * 16 + nl) * G2 + k0 + quad * 8);
    for (int mt = 0; mt < 2; ++mt)
      for (int nt = 0; nt < 4; ++nt)
        acc[mt][nt] = mfma16(a[mt], bfr[nt], acc[mt][nt]);
  }
  for (int mt = 0; mt < 2; ++mt)
    for (int nt = 0; nt < 4; ++nt)
      for (int r = 0; r < 4; ++r) {
        int row = wave * 32 + mt * 16 + quad * 4 + r;
        int col = nt * 16 + nl;
        float v = acc[mt][nt][r] + bf2fs(T2[(size_t)row * NE + col]);
        Hp[(size_t)row * Kk + col] = f2bfs(fmaxf(v, 0.f));
      }
}

// ---------------- K7: out = Wh @ H^T + residual ------------------------------
__global__ void k_outgemm(const short* __restrict__ whb, const short* __restrict__ h,
                          const float* __restrict__ txt, const float* __restrict__ aud,
                          const float* __restrict__ vis, float* __restrict__ outp) {
  int s0 = blockIdx.x * 128, b = blockIdx.y, mod = blockIdx.z;
  const short* Wp = whb + (size_t)mod * Ss * Kk;
  const short* Hp = h + ((size_t)mod * Bb + b) * Ff * Kk;
  const float* xres = ((mod == 0) ? aud : (mod == 1) ? vis : txt) + (size_t)b * Ss * Ff;
  int slot = (mod == 0) ? 1 : (mod == 1) ? 2 : 0;   // output order (t, a, v)
  float* Op = outp + ((size_t)slot * Bb + b) * Ss * Ff;
  int tid = threadIdx.x, lane = tid & 63, wave = tid >> 6;
  int quad = lane >> 4, nl = lane & 15;
  int wm = (wave >> 1) * 64, wn = (wave & 1) * 64;
  facc zero = {0.f, 0.f, 0.f, 0.f};
  facc acc[4][4];
  for (int i = 0; i < 4; ++i) for (int j = 0; j < 4; ++j) acc[i][j] = zero;
  for (int k0 = 0; k0 < Kk; k0 += 32) {
    bfrag a[4], bfr[4];
    for (int mt = 0; mt < 4; ++mt)
      a[mt] = *(const bfrag*)(Wp + (size_t)(s0 + wm + mt * 16 + nl) * Kk + k0 + quad * 8);
    for (int nt = 0; nt < 4; ++nt)
      bfr[nt] = *(const bfrag*)(Hp + (size_t)(wn + nt * 16 + nl) * Kk + k0 + quad * 8);
    for (int mt = 0; mt < 4; ++mt)
      for (int nt = 0; nt < 4; ++nt)
        acc[mt][nt] = mfma16(a[mt], bfr[nt], acc[mt][nt]);
  }
  for (int mt = 0; mt < 4; ++mt)
    for (int nt = 0; nt < 4; ++nt)
      for (int r = 0; r < 4; ++r) {
        int srow = s0 + wm + mt * 16 + quad * 4 + r;
        int col = wn + nt * 16 + nl;
        size_t o = (size_t)srow * Ff + col;
        Op[o] = acc[mt][nt][r] + xres[o];
      }
}

extern "C" void kernel_launch(void* const* d_in, const int* in_sizes, int n_in,
                              void* d_out, int out_size, void* d_ws, size_t ws_size,
                              hipStream_t stream) {
  const float* txt = (const float*)d_in[0];
  const float* aud = (const float*)d_in[1];
  const float* vis = (const float*)d_in[2];
  const float* Wi  = (const float*)d_in[3];
  const float* bi  = (const float*)d_in[4];
  const float* Wq  = (const float*)d_in[5];
  const float* bq  = (const float*)d_in[6];
  const float* Wvp = (const float*)d_in[7];
  const float* bvp = (const float*)d_in[8];
  const float* Aa  = (const float*)d_in[9];
  const float* Av  = (const float*)d_in[10];
  const float* Al  = (const float*)d_in[11];
  const float* Wa  = (const float*)d_in[12];
  const float* Wv  = (const float*)d_in[13];
  const float* Wt  = (const float*)d_in[14];
  const float* Wca = (const float*)d_in[15];
  const float* Wcv = (const float*)d_in[16];
  const float* Wct = (const float*)d_in[17];
  const float* Wha = (const float*)d_in[18];
  const float* Whv = (const float*)d_in[19];
  const float* Wht = (const float*)d_in[20];

  char* w = (char*)d_ws;
  float* sumsq  = (float*)w;                    // 3 floats
  float* colnsq = (float*)(w + 256);            // B*F floats
  size_t off = 65536;
  short* xT    = (short*)(w + off); off += (size_t)3 * Bb * Ff * Ss * 2;   // 48MB
  short* aextT = (short*)(w + off); off += (size_t)3 * NE * Ss * 2;        // 6.75MB
  short* gT    = (short*)(w + off); off += (size_t)Bb * Ff * Ss * 2;       // 16MB
  short* mx    = (short*)(w + off);                                        // 54MB
  short* p1    = mx;                             // p1/p2 overlaid under mx:
  short* p2    = mx + (size_t)Bb * Ss * Ff;      // dead before k_mgemm writes
  off += (size_t)3 * Bb * Ff * NE * 2;
  short* cc    = (short*)(w + off); off += (size_t)3 * Bb * Ff * G2 * 2;   // 12MB
  short* h     = (short*)(w + off); off += (size_t)3 * Bb * Ff * Kk * 2;   // 3MB
  short* wcb   = (short*)(w + off); off += (size_t)3 * Kk * G2 * 2;
  short* whb   = (short*)(w + off); off += (size_t)3 * Ss * Kk * 2;
  short* wbar  = (short*)(w + off); off += (size_t)3 * G2 * Ff * 2;

  hipMemsetAsync(d_ws, 0, 65536, stream);   // zero sumsq + colnsq
  k_transpose<<<dim3(16, 2, 192), 256, 0, stream>>>(aud, vis, txt, xT);
  k_build_aextT<<<dim3(NE / 64, 16, 3), 256, 0, stream>>>(Aa, Av, Al, Wa, Wv, Wt, aextT);
  k_build_w<<<(3 * Kk * G2 + 3 * Ss * Kk + 3 * G2 * Ff) / 256, 256, 0, stream>>>(
      Wca, Wcv, Wct, Wha, Whv, Wht, Wi, Wq, Wvp, wcb, whb, wbar);
  k_amlp<<<dim3(Bb * Ss / 256, 3), 256, 0, stream>>>(txt, aud, vis, bi, bq, bvp,
                                                     wbar, p1, p2, sumsq);
  k_colnorm<<<dim3(Bb, 16), 128, 0, stream>>>(p1, p2, sumsq, colnsq);
  k_gnormT<<<dim3(16, 2, Bb), 256, 0, stream>>>(p1, p2, sumsq, colnsq, gT);
  k_mgemm<<<dim3(Bb * Ff / 128, NE / 128, 3), 256, 0, stream>>>(xT, aextT, mx);
  k_cgemm<<<dim3(Bb, 4, 3), 256, 0, stream>>>(mx, xT, gT, cc);
  k_hgemm<<<dim3(Bb, 3), 256, 0, stream>>>(cc, wcb, mx, h);
  k_outgemm<<<dim3(Ss / 128, Bb, 3), 256, 0, stream>>>(whb, h, txt, aud, vis, (float*)d_out);
}

// Round 4
// 471.294 us; speedup vs baseline: 1.6665x; 1.0146x over previous
//
#include <hip/hip_runtime.h>
#include <math.h>

constexpr int Bb = 64;
constexpr int Ss = 1024;
constexpr int Ff = 128;
constexpr int G2 = 256;   // 2F
constexpr int Kk = 64;
constexpr int NE = 1152;  // S + 64 (W^T cols) + 64 pad

typedef __bf16 bfrag __attribute__((ext_vector_type(8)));
typedef float  facc  __attribute__((ext_vector_type(4)));
typedef short  s8v   __attribute__((ext_vector_type(8)));

__device__ __forceinline__ short f2bfs(float f) {
  union { float f; unsigned u; } v; v.f = f;
  unsigned r = v.u + 0x7FFFu + ((v.u >> 16) & 1u);
  return (short)(r >> 16);
}
__device__ __forceinline__ float bf2fs(short s) {
  union { unsigned u; float f; } v; v.u = ((unsigned)(unsigned short)s) << 16;
  return v.f;
}
__device__ __forceinline__ facc mfma16(bfrag a, bfrag b, facc c) {
  return __builtin_amdgcn_mfma_f32_16x16x32_bf16(a, b, c, 0, 0, 0);
}
// async global->LDS, 16B per lane; LDS dest must be wave-uniform base + lane*16
__device__ __forceinline__ void gld16(const void* g, void* l) {
  __builtin_amdgcn_global_load_lds(
      (const __attribute__((address_space(1))) void*)g,
      (__attribute__((address_space(3))) void*)l, 16, 0, 0);
}

// ---------------- K0a: transpose+convert x -> xT bf16 [3][B][F][S] ------------
__global__ void k_transpose(const float* __restrict__ aud, const float* __restrict__ vis,
                            const float* __restrict__ txt, short* __restrict__ xT) {
  __shared__ float tile[64][65];
  int z = blockIdx.z;                 // mod*B + b
  int mod = z >> 6, b = z & 63;
  const float* x = (mod == 0) ? aud : (mod == 1) ? vis : txt;
  int s0 = blockIdx.x * 64, f0 = blockIdx.y * 64;
  int tid = threadIdx.x;
  for (int i = 0; i < 16; ++i) {
    int idx = i * 256 + tid;
    int si = idx >> 6, fi = idx & 63;
    tile[si][fi] = x[((size_t)b * Ss + s0 + si) * Ff + f0 + fi];
  }
  __syncthreads();
  short* dst = xT + ((size_t)mod * Bb + b) * Ff * Ss;
  for (int i = 0; i < 16; ++i) {
    int idx = i * 256 + tid;
    int fi = idx >> 6, si = idx & 63;
    dst[(size_t)(f0 + fi) * Ss + s0 + si] = f2bfs(tile[si][fi]);
  }
}

// ---------------- K0b: build AextT bf16 [3][NE][S]; row n: (A^T | W | 0) -----
__global__ void k_build_aextT(const float* __restrict__ Aa, const float* __restrict__ Av,
                              const float* __restrict__ Al, const float* __restrict__ Wa,
                              const float* __restrict__ Wv, const float* __restrict__ Wt,
                              short* __restrict__ aextT) {
  __shared__ float tile[64][65];
  int mod = blockIdx.z;
  const float* A = (mod == 0) ? Aa : (mod == 1) ? Av : Al;
  const float* W = (mod == 0) ? Wa : (mod == 1) ? Wv : Wt;
  short* dst = aextT + (size_t)mod * NE * Ss;
  int n0 = blockIdx.x * 64, t0 = blockIdx.y * 64;
  int tid = threadIdx.x;
  if (n0 < Ss) {
    for (int i = 0; i < 16; ++i) {
      int idx = i * 256 + tid;
      int ti = idx >> 6, nj = idx & 63;
      tile[ti][nj] = A[(size_t)(t0 + ti) * Ss + n0 + nj];
    }
    __syncthreads();
    for (int i = 0; i < 16; ++i) {
      int idx = i * 256 + tid;
      int nj = idx >> 6, ti = idx & 63;
      dst[(size_t)(n0 + nj) * Ss + t0 + ti] = f2bfs(tile[ti][nj]);
    }
  } else if (n0 < Ss + Kk) {
    for (int i = 0; i < 16; ++i) {
      int idx = i * 256 + tid;
      int j = idx >> 6, tt = idx & 63;
      dst[(size_t)(n0 + j) * Ss + t0 + tt] = f2bfs(W[(size_t)(n0 - Ss + j) * Ss + t0 + tt]);
    }
  } else {
    for (int i = 0; i < 16; ++i) {
      int idx = i * 256 + tid;
      int j = idx >> 6, tt = idx & 63;
      dst[(size_t)(n0 + j) * Ss + t0 + tt] = 0;
    }
  }
}

// ---------------- K0c: convert Wc, Wh; arrange AMLP W into LDS frag layout ----
__global__ void k_build_w(const float* __restrict__ Wca, const float* __restrict__ Wcv,
                          const float* __restrict__ Wct, const float* __restrict__ Wha,
                          const float* __restrict__ Whv, const float* __restrict__ Wht,
                          const float* __restrict__ Wi, const float* __restrict__ Wq,
                          const float* __restrict__ Wvp,
                          short* __restrict__ wcb, short* __restrict__ whb,
                          short* __restrict__ wbar) {
  int idx = blockIdx.x * 256 + threadIdx.x;
  const int n1 = 3 * Kk * G2;                // 49152
  const int n2 = n1 + 3 * Ss * Kk;           // 245760
  if (idx < n1) {
    int mod = idx / (Kk * G2), r = idx - mod * (Kk * G2);
    const float* W = (mod == 0) ? Wca : (mod == 1) ? Wcv : Wct;
    wcb[idx] = f2bfs(W[r]);
  } else if (idx < n2) {
    int j = idx - n1;
    int mod = j / (Ss * Kk), r = j - mod * (Ss * Kk);
    const float* W = (mod == 0) ? Wha : (mod == 1) ? Whv : Wht;
    whb[j] = f2bfs(W[r]);
  } else {
    int j = idx - n2;                        // < 3*G2*Ff
    int mod = j / (G2 * Ff), r = j - mod * (G2 * Ff);
    int n = r >> 7, k = r & 127;
    const float* W = (mod == 0) ? Wi : (mod == 1) ? Wq : Wvp;
    // layout: [(k>>3)][n][k&7] — fragment-contiguous 16B reads in k_amlp
    wbar[mod * G2 * Ff + (((k >> 3) * G2 + n) * 8) + (k & 7)] = f2bfs(W[r]);
  }
}

// ---------------- K1: AMLP f-GEMM, pooled p out + global sum(f^2) -------------
__global__ void __launch_bounds__(256) k_amlp(
    const float* __restrict__ txt, const float* __restrict__ aud, const float* __restrict__ vis,
    const float* __restrict__ bi, const float* __restrict__ bq, const float* __restrict__ bvp,
    const short* __restrict__ wbar,
    short* __restrict__ p1, short* __restrict__ p2, float* __restrict__ sumsq) {
  int mod = blockIdx.y;
  const float* x    = (mod == 0) ? txt : (mod == 1) ? aud : vis;
  const float* bias = (mod == 0) ? bi  : (mod == 1) ? bq  : bvp;
  const short* wbm  = wbar + mod * G2 * Ff;
  short* pout = (mod == 0) ? p1 : (mod == 1) ? p2 : nullptr;

  __shared__ short wlds[G2 * Ff];   // 64KB, pre-arranged layout
  __shared__ float wred[4];
  int tid = threadIdx.x, lane = tid & 63, wave = tid >> 6;
  int quad = lane >> 4, nl = lane & 15;
  for (int i = 0; i < 16; ++i) {     // async linear copy
    int o = (i * 256 + tid) * 8;
    gld16(wbm + o, wlds + o);
  }
  __syncthreads();

  float bia[16];
  for (int t = 0; t < 16; ++t) bia[t] = bias[t * 16 + nl];

  facc zero = {0.f, 0.f, 0.f, 0.f};
  float sq = 0.f;
  for (int rg = 0; rg < 4; ++rg) {
    int arow = blockIdx.x * 256 + rg * 64 + wave * 16 + nl;   // A row (m = lane&15)
    const float* xrow = x + (size_t)arow * Ff;
    facc acc[16];
    for (int t = 0; t < 16; ++t) acc[t] = zero;
    for (int k0 = 0; k0 < Ff; k0 += 32) {
      float4 a0 = *(const float4*)(xrow + k0 + quad * 8);
      float4 a1 = *(const float4*)(xrow + k0 + quad * 8 + 4);
      bfrag af;
      af[0]=(__bf16)a0.x; af[1]=(__bf16)a0.y; af[2]=(__bf16)a0.z; af[3]=(__bf16)a0.w;
      af[4]=(__bf16)a1.x; af[5]=(__bf16)a1.y; af[6]=(__bf16)a1.z; af[7]=(__bf16)a1.w;
      int chunk = (k0 >> 3) + quad;
      for (int t = 0; t < 16; ++t) {
        bfrag bfr = *(const bfrag*)(wlds + ((size_t)chunk * G2 + t * 16 + nl) * 8);
        acc[t] = mfma16(af, bfr, acc[t]);
      }
    }
    int drow = blockIdx.x * 256 + rg * 64 + wave * 16 + quad * 4;  // D row (m=quad*4+r)
    for (int t = 0; t < 16; ++t) {
      for (int r = 0; r < 4; ++r) {
        float fv = acc[t][r] + bia[t];
        sq += fv * fv;
        if (pout) {
          float fo = fv + __shfl_xor(fv, 1, 64);       // pair-pool along n
          if ((lane & 1) == 0)
            pout[(size_t)(drow + r) * Ff + t * 8 + (nl >> 1)] = f2bfs(fo);
        }
      }
    }
  }
  for (int off = 32; off > 0; off >>= 1) sq += __shfl_down(sq, off, 64);
  if (lane == 0) wred[wave] = sq;
  __syncthreads();
  if (tid == 0) atomicAdd(&sumsq[mod], wred[0] + wred[1] + wred[2] + wred[3]);
}

// ---------------- K2: column norms over s of z -------------------------------
__global__ void k_colnorm(const short* __restrict__ p1, const short* __restrict__ p2,
                          const float* __restrict__ sumsq, float* __restrict__ colnsq) {
  float n1 = sqrtf(sumsq[0]), n2 = sqrtf(sumsq[1]), n3 = sqrtf(sumsq[2]);
  float w1 = n1 / (n1 + n2), w2 = n2 / (n1 + n2);
  float tc = 2.f * n3 * n3 / (n1 + n2 + n3);
  int b = blockIdx.x, j = threadIdx.x;
  int s0 = blockIdx.y * 64;
  float a = 0.f;
  for (int s = s0; s < s0 + 64; ++s) {
    size_t off = ((size_t)b * Ss + s) * Ff + j;
    float z = w1 * bf2fs(p1[off]) + w2 * bf2fs(p2[off]) + tc;
    a += z * z;
  }
  atomicAdd(&colnsq[b * Ff + j], a);
}

// ---------------- K3: gT[b][f][s] = z / max(colnorm,1e-12), tiled transpose ---
__global__ void k_gnormT(const short* __restrict__ p1, const short* __restrict__ p2,
                         const float* __restrict__ sumsq, const float* __restrict__ colnsq,
                         short* __restrict__ gT) {
  __shared__ float tile[64][65];
  float n1 = sqrtf(sumsq[0]), n2 = sqrtf(sumsq[1]), n3 = sqrtf(sumsq[2]);
  float w1 = n1 / (n1 + n2), w2 = n2 / (n1 + n2);
  float tc = 2.f * n3 * n3 / (n1 + n2 + n3);
  int b = blockIdx.z, s0 = blockIdx.x * 64, f0 = blockIdx.y * 64;
  int tid = threadIdx.x;
  for (int i = 0; i < 16; ++i) {
    int idx = i * 256 + tid;
    int si = idx >> 6, fi = idx & 63;
    size_t off = ((size_t)b * Ss + s0 + si) * Ff + f0 + fi;
    float z = w1 * bf2fs(p1[off]) + w2 * bf2fs(p2[off]) + tc;
    float cn = fmaxf(sqrtf(colnsq[b * Ff + f0 + fi]), 1e-12f);
    tile[si][fi] = z / cn;
  }
  __syncthreads();
  short* dst = gT + (size_t)b * Ff * Ss;
  for (int i = 0; i < 16; ++i) {
    int idx = i * 256 + tid;
    int fi = idx >> 6, si = idx & 63;
    dst[(size_t)(f0 + fi) * Ss + s0 + si] = f2bfs(tile[si][fi]);
  }
}

// ---------------- K4: M-GEMM, BK=64, XOR-swizzled LDS ------------------------
// LDS slot (r, c) holds global 16B-chunk (c ^ (r&7)) of row r -> fragment
// reads land 2 lanes/bank (free); global loads stay within-row permuted
// (fully coalesced).
__global__ void __launch_bounds__(256) k_mgemm(const short* __restrict__ xT,
                                               const short* __restrict__ aextT,
                                               short* __restrict__ mxext) {
  int mod = blockIdx.z;
  const short* Ap = xT + (size_t)mod * Bb * Ff * Ss;
  const short* Bp = aextT + (size_t)mod * NE * Ss;
  short* Op = mxext + (size_t)mod * Bb * Ff * NE;
  int M0 = blockIdx.x * 128, N0 = blockIdx.y * 128;
  __shared__ short As[128 * 64];   // 16KB
  __shared__ short Bs[128 * 64];   // 16KB
  int tid = threadIdx.x, lane = tid & 63, wave = tid >> 6;
  int quad = lane >> 4, nl = lane & 15;
  int wm = (wave >> 1) * 64, wn = (wave & 1) * 64;
  facc zero = {0.f, 0.f, 0.f, 0.f};
  facc acc[4][4];
  for (int i = 0; i < 4; ++i) for (int j = 0; j < 4; ++j) acc[i][j] = zero;
  for (int k0 = 0; k0 < Ss; k0 += 64) {
    __syncthreads();
#pragma unroll
    for (int i = 0; i < 4; ++i) {
      int idx = i * 256 + tid;
      int r = idx >> 3, cs = ((idx & 7) ^ (r & 7)) * 8;
      gld16(Ap + (size_t)(M0 + r) * Ss + k0 + cs, As + idx * 8);
      gld16(Bp + (size_t)(N0 + r) * Ss + k0 + cs, Bs + idx * 8);
    }
    __syncthreads();
#pragma unroll
    for (int kc = 0; kc < 2; ++kc) {
      bfrag a[4], bfr[4];
      for (int mt = 0; mt < 4; ++mt) {
        int row = wm + mt * 16 + nl;
        a[mt] = *(const bfrag*)(As + row * 64 + (((kc * 4 + quad) ^ (row & 7)) * 8));
      }
      for (int nt = 0; nt < 4; ++nt) {
        int row = wn + nt * 16 + nl;
        bfr[nt] = *(const bfrag*)(Bs + row * 64 + (((kc * 4 + quad) ^ (row & 7)) * 8));
      }
      for (int mt = 0; mt < 4; ++mt)
        for (int nt = 0; nt < 4; ++nt)
          acc[mt][nt] = mfma16(a[mt], bfr[nt], acc[mt][nt]);
    }
  }
  for (int mt = 0; mt < 4; ++mt)
    for (int nt = 0; nt < 4; ++nt)
      for (int r = 0; r < 4; ++r) {
        int row = M0 + wm + mt * 16 + quad * 4 + r;
        int col = N0 + wn + nt * 16 + nl;
        Op[(size_t)row * NE + col] = f2bfs(acc[mt][nt][r]);
      }
}

// ---------------- K5: fused C-GEMM + H-GEMM ----------------------------------
// One 512-thread block per (b,mod): C = tanh((M @ [x|G])/16) for the full
// 128x256 tile (BK=64 swizzled staging), C -> LDS (stride 272), then
// H = relu(C @ Wc^T + T2) written to h. Removes the cc intermediate.
__global__ void __launch_bounds__(512) k_chgemm(const short* __restrict__ mxext,
                                                const short* __restrict__ xT,
                                                const short* __restrict__ gT,
                                                const short* __restrict__ wcb,
                                                short* __restrict__ h) {
  int b = blockIdx.x, mod = blockIdx.y;
  const short* Ap = mxext + ((size_t)mod * Bb + b) * Ff * NE;
  // a,v use aud (xT slot 0, source bug); t uses txt (slot 2)
  const short* xTb = xT + (size_t)((mod == 2) ? 2 : 0) * Bb * Ff * Ss + (size_t)b * Ff * Ss;
  const short* gTb = gT + (size_t)b * Ff * Ss;
  const short* Wp = wcb + (size_t)mod * Kk * G2;
  short* Hp = h + ((size_t)mod * Bb + b) * Ff * Kk;

  __shared__ short smem[128 * 272];          // 69.6KB
  short* As = smem;                          // [128][64] staging
  short* Bs = smem + 128 * 64;               // [256][64] staging
  // Cs = smem reused as [128][272] after staging is dead

  int tid = threadIdx.x, lane = tid & 63, wave = tid >> 6;
  int quad = lane >> 4, nl = lane & 15;
  int wm = (wave >> 2) * 64, wn = (wave & 3) * 64;
  facc zero = {0.f, 0.f, 0.f, 0.f};
  facc acc[4][4];
  for (int i = 0; i < 4; ++i) for (int j = 0; j < 4; ++j) acc[i][j] = zero;
  for (int k0 = 0; k0 < Ss; k0 += 64) {
    __syncthreads();
#pragma unroll
    for (int i = 0; i < 2; ++i) {            // A: 128 rows
      int idx = i * 512 + tid;
      int r = idx >> 3, cs = ((idx & 7) ^ (r & 7)) * 8;
      gld16(Ap + (size_t)r * NE + k0 + cs, As + idx * 8);
    }
#pragma unroll
    for (int i = 0; i < 4; ++i) {            // B: 256 rows (128 x | 128 g)
      int idx = i * 512 + tid;
      int r = idx >> 3, cs = ((idx & 7) ^ (r & 7)) * 8;
      const short* src = (r < 128) ? (xTb + (size_t)r * Ss) : (gTb + (size_t)(r - 128) * Ss);
      gld16(src + k0 + cs, Bs + idx * 8);
    }
    __syncthreads();
#pragma unroll
    for (int kc = 0; kc < 2; ++kc) {
      bfrag a[4], bfr[4];
      for (int mt = 0; mt < 4; ++mt) {
        int row = wm + mt * 16 + nl;
        a[mt] = *(const bfrag*)(As + row * 64 + (((kc * 4 + quad) ^ (row & 7)) * 8));
      }
      for (int nt = 0; nt < 4; ++nt) {
        int row = wn + nt * 16 + nl;
        bfr[nt] = *(const bfrag*)(Bs + row * 64 + (((kc * 4 + quad) ^ (row & 7)) * 8));
      }
      for (int mt = 0; mt < 4; ++mt)
        for (int nt = 0; nt < 4; ++nt)
          acc[mt][nt] = mfma16(a[mt], bfr[nt], acc[mt][nt]);
    }
  }
  __syncthreads();                            // staging dead; reuse smem as Cs
  short* Cs = smem;
  for (int mt = 0; mt < 4; ++mt)
    for (int nt = 0; nt < 4; ++nt)
      for (int r = 0; r < 4; ++r) {
        int row = wm + mt * 16 + quad * 4 + r;
        int col = wn + nt * 16 + nl;
        Cs[row * 272 + col] = f2bfs(tanhf(acc[mt][nt][r] * 0.0625f));
      }
  __syncthreads();
  // H phase: wave w handles C rows [16w, 16w+16)
  facc hacc[4];
  for (int nt = 0; nt < 4; ++nt) hacc[nt] = zero;
  for (int k0 = 0; k0 < G2; k0 += 32) {
    bfrag ca = *(const bfrag*)(Cs + (wave * 16 + nl) * 272 + k0 + quad * 8);
    for (int nt = 0; nt < 4; ++nt) {
      bfrag wb = *(const bfrag*)(Wp + (size_t)(nt * 16 + nl) * G2 + k0 + quad * 8);
      hacc[nt] = mfma16(ca, wb, hacc[nt]);
    }
  }
  for (int nt = 0; nt < 4; ++nt)
    for (int r = 0; r < 4; ++r) {
      int row = wave * 16 + quad * 4 + r;
      int col = nt * 16 + nl;
      float v = hacc[nt][r] + bf2fs(Ap[(size_t)row * NE + Ss + col]);  // + T2
      Hp[(size_t)row * Kk + col] = f2bfs(fmaxf(v, 0.f));
    }
}

// ---------------- K7: out = Wh @ H^T + residual ------------------------------
__global__ void k_outgemm(const short* __restrict__ whb, const short* __restrict__ h,
                          const float* __restrict__ txt, const float* __restrict__ aud,
                          const float* __restrict__ vis, float* __restrict__ outp) {
  int s0 = blockIdx.x * 128, b = blockIdx.y, mod = blockIdx.z;
  const short* Wp = whb + (size_t)mod * Ss * Kk;
  const short* Hp = h + ((size_t)mod * Bb + b) * Ff * Kk;
  const float* xres = ((mod == 0) ? aud : (mod == 1) ? vis : txt) + (size_t)b * Ss * Ff;
  int slot = (mod == 0) ? 1 : (mod == 1) ? 2 : 0;   // output order (t, a, v)
  float* Op = outp + ((size_t)slot * Bb + b) * Ss * Ff;
  int tid = threadIdx.x, lane = tid & 63, wave = tid >> 6;
  int quad = lane >> 4, nl = lane & 15;
  int wm = (wave >> 1) * 64, wn = (wave & 1) * 64;
  facc zero = {0.f, 0.f, 0.f, 0.f};
  facc acc[4][4];
  for (int i = 0; i < 4; ++i) for (int j = 0; j < 4; ++j) acc[i][j] = zero;
  for (int k0 = 0; k0 < Kk; k0 += 32) {
    bfrag a[4], bfr[4];
    for (int mt = 0; mt < 4; ++mt)
      a[mt] = *(const bfrag*)(Wp + (size_t)(s0 + wm + mt * 16 + nl) * Kk + k0 + quad * 8);
    for (int nt = 0; nt < 4; ++nt)
      bfr[nt] = *(const bfrag*)(Hp + (size_t)(wn + nt * 16 + nl) * Kk + k0 + quad * 8);
    for (int mt = 0; mt < 4; ++mt)
      for (int nt = 0; nt < 4; ++nt)
        acc[mt][nt] = mfma16(a[mt], bfr[nt], acc[mt][nt]);
  }
  for (int mt = 0; mt < 4; ++mt)
    for (int nt = 0; nt < 4; ++nt)
      for (int r = 0; r < 4; ++r) {
        int srow = s0 + wm + mt * 16 + quad * 4 + r;
        int col = wn + nt * 16 + nl;
        size_t o = (size_t)srow * Ff + col;
        Op[o] = acc[mt][nt][r] + xres[o];
      }
}

extern "C" void kernel_launch(void* const* d_in, const int* in_sizes, int n_in,
                              void* d_out, int out_size, void* d_ws, size_t ws_size,
                              hipStream_t stream) {
  const float* txt = (const float*)d_in[0];
  const float* aud = (const float*)d_in[1];
  const float* vis = (const float*)d_in[2];
  const float* Wi  = (const float*)d_in[3];
  const float* bi  = (const float*)d_in[4];
  const float* Wq  = (const float*)d_in[5];
  const float* bq  = (const float*)d_in[6];
  const float* Wvp = (const float*)d_in[7];
  const float* bvp = (const float*)d_in[8];
  const float* Aa  = (const float*)d_in[9];
  const float* Av  = (const float*)d_in[10];
  const float* Al  = (const float*)d_in[11];
  const float* Wa  = (const float*)d_in[12];
  const float* Wv  = (const float*)d_in[13];
  const float* Wt  = (const float*)d_in[14];
  const float* Wca = (const float*)d_in[15];
  const float* Wcv = (const float*)d_in[16];
  const float* Wct = (const float*)d_in[17];
  const float* Wha = (const float*)d_in[18];
  const float* Whv = (const float*)d_in[19];
  const float* Wht = (const float*)d_in[20];

  char* w = (char*)d_ws;
  float* sumsq  = (float*)w;                    // 3 floats
  float* colnsq = (float*)(w + 256);            // B*F floats
  size_t off = 65536;
  short* xT    = (short*)(w + off); off += (size_t)3 * Bb * Ff * Ss * 2;   // 48MB
  short* aextT = (short*)(w + off); off += (size_t)3 * NE * Ss * 2;        // 6.75MB
  short* gT    = (short*)(w + off); off += (size_t)Bb * Ff * Ss * 2;       // 16MB
  short* mx    = (short*)(w + off);                                        // 54MB
  short* p1    = mx;                             // p1/p2 overlaid under mx:
  short* p2    = mx + (size_t)Bb * Ss * Ff;      // dead before k_mgemm writes
  off += (size_t)3 * Bb * Ff * NE * 2;
  short* h     = (short*)(w + off); off += (size_t)3 * Bb * Ff * Kk * 2;   // 3MB
  short* wcb   = (short*)(w + off); off += (size_t)3 * Kk * G2 * 2;
  short* whb   = (short*)(w + off); off += (size_t)3 * Ss * Kk * 2;
  short* wbar  = (short*)(w + off); off += (size_t)3 * G2 * Ff * 2;

  hipMemsetAsync(d_ws, 0, 65536, stream);   // zero sumsq + colnsq
  k_transpose<<<dim3(16, 2, 192), 256, 0, stream>>>(aud, vis, txt, xT);
  k_build_aextT<<<dim3(NE / 64, 16, 3), 256, 0, stream>>>(Aa, Av, Al, Wa, Wv, Wt, aextT);
  k_build_w<<<(3 * Kk * G2 + 3 * Ss * Kk + 3 * G2 * Ff) / 256, 256, 0, stream>>>(
      Wca, Wcv, Wct, Wha, Whv, Wht, Wi, Wq, Wvp, wcb, whb, wbar);
  k_amlp<<<dim3(Bb * Ss / 256, 3), 256, 0, stream>>>(txt, aud, vis, bi, bq, bvp,
                                                     wbar, p1, p2, sumsq);
  k_colnorm<<<dim3(Bb, 16), 128, 0, stream>>>(p1, p2, sumsq, colnsq);
  k_gnormT<<<dim3(16, 2, Bb), 256, 0, stream>>>(p1, p2, sumsq, colnsq, gT);
  k_mgemm<<<dim3(Bb * Ff / 128, NE / 128, 3), 256, 0, stream>>>(xT, aextT, mx);
  k_chgemm<<<dim3(Bb, 3), 512, 0, stream>>>(mx, xT, gT, wcb, h);
  k_outgemm<<<dim3(Ss / 128, Bb, 3), 256, 0, stream>>>(whb, h, txt, aud, vis, (float*)d_out);
}